// Round 1
// baseline (917.412 us; speedup 1.0000x reference)
//
#include <hip/hip_runtime.h>

#define NN 100000
#define NE 1600000
#define KDIM 128

// ---------------- degree count (self-loop folded in as +1 later) ----------------
__global__ __launch_bounds__(256) void k_degree(const int* __restrict__ src,
                                                const int* __restrict__ dst,
                                                unsigned* __restrict__ cnt_out,
                                                unsigned* __restrict__ cnt_in) {
    int e = blockIdx.x * 256 + threadIdx.x;
    if (e < NE) {
        atomicAdd(&cnt_out[src[e]], 1u);
        atomicAdd(&cnt_in[dst[e]], 1u);
    }
}

__global__ __launch_bounds__(256) void k_rsqrt(const unsigned* __restrict__ cnt_out,
                                               const unsigned* __restrict__ cnt_in,
                                               float* __restrict__ oi,
                                               float* __restrict__ ii) {
    int i = blockIdx.x * 256 + threadIdx.x;
    if (i < NN) {
        oi[i] = rsqrtf((float)(cnt_out[i] + 1u));  // deg includes self loop -> >=1
        ii[i] = rsqrtf((float)(cnt_in[i] + 1u));
    }
}

// ---------------- exclusive scan of in-counts -> CSR row starts ----------------
__global__ __launch_bounds__(256) void k_scan1(const unsigned* __restrict__ cnt,
                                               unsigned* __restrict__ incl,
                                               unsigned* __restrict__ bsums) {
    __shared__ unsigned s[256];
    int i = blockIdx.x * 256 + threadIdx.x;
    unsigned v = (i < NN) ? cnt[i] : 0u;
    s[threadIdx.x] = v;
    __syncthreads();
    for (int off = 1; off < 256; off <<= 1) {
        unsigned x = s[threadIdx.x];
        if (threadIdx.x >= off) x += s[threadIdx.x - off];
        __syncthreads();
        s[threadIdx.x] = x;
        __syncthreads();
    }
    if (i < NN) incl[i] = s[threadIdx.x];
    if (threadIdx.x == 255) bsums[blockIdx.x] = s[255];
}

__global__ __launch_bounds__(512) void k_scan2(unsigned* __restrict__ bsums, int nb) {
    __shared__ unsigned s[512];
    int t = threadIdx.x;
    s[t] = (t < nb) ? bsums[t] : 0u;
    __syncthreads();
    for (int off = 1; off < 512; off <<= 1) {
        unsigned x = s[t];
        if (t >= off) x += s[t - off];
        __syncthreads();
        s[t] = x;
        __syncthreads();
    }
    if (t < nb) bsums[t] = s[t];  // inclusive block sums
}

__global__ __launch_bounds__(256) void k_scan3(const unsigned* __restrict__ incl,
                                               const unsigned* __restrict__ cnt,
                                               const unsigned* __restrict__ bsums,
                                               unsigned* __restrict__ row_start,
                                               unsigned* __restrict__ cursor) {
    int i = blockIdx.x * 256 + threadIdx.x;
    if (i < NN) {
        unsigned prefix = (blockIdx.x > 0) ? bsums[blockIdx.x - 1] : 0u;
        unsigned rs = prefix + incl[i] - cnt[i];  // exclusive
        row_start[i] = rs;
        cursor[i] = rs;
    }
}

__global__ __launch_bounds__(256) void k_fill(const int* __restrict__ src,
                                              const int* __restrict__ dst,
                                              unsigned* __restrict__ cursor,
                                              unsigned* __restrict__ csr) {
    int e = blockIdx.x * 256 + threadIdx.x;
    if (e < NE) {
        unsigned p = atomicAdd(&cursor[dst[e]], 1u);
        csr[p] = (unsigned)src[e];
    }
}

// ---------------- aggregation: wave per node, gather over CSR ----------------
// Layer 1: input = raw feat, scale each gathered row by oi[src] on the fly.
__global__ __launch_bounds__(256) void k_agg1(const float* __restrict__ feat,
                                              const float* __restrict__ oi,
                                              const float* __restrict__ ii,
                                              const unsigned* __restrict__ row_start,
                                              const unsigned* __restrict__ cnt_in,
                                              const unsigned* __restrict__ csr,
                                              float* __restrict__ out) {
    int wid = (int)((blockIdx.x * 256u + threadIdx.x) >> 6);
    int lane = threadIdx.x & 63;
    if (wid >= NN) return;
    float2 acc;
    {
        float sc = oi[wid];  // self loop
        float2 v = *(const float2*)(feat + (size_t)wid * KDIM + lane * 2);
        acc.x = v.x * sc;
        acc.y = v.y * sc;
    }
    unsigned rs = row_start[wid];
    unsigned nk = cnt_in[wid];
    unsigned snext = nk ? csr[rs] : 0u;
    for (unsigned k = 0; k < nk; ++k) {
        unsigned s = snext;
        if (k + 1 < nk) snext = csr[rs + k + 1];
        float sc = oi[s];
        float2 v = *(const float2*)(feat + (size_t)s * KDIM + lane * 2);
        acc.x = fmaf(v.x, sc, acc.x);
        acc.y = fmaf(v.y, sc, acc.y);
    }
    float si = ii[wid];
    float2 r;
    r.x = acc.x * si;
    r.y = acc.y * si;
    *(float2*)(out + (size_t)wid * KDIM + lane * 2) = r;
}

// Layers 2/3: input rows already carry the out_isqrt scale (fused into GEMM epilogue).
__global__ __launch_bounds__(256) void k_agg(const float* __restrict__ h,
                                             const float* __restrict__ ii,
                                             const unsigned* __restrict__ row_start,
                                             const unsigned* __restrict__ cnt_in,
                                             const unsigned* __restrict__ csr,
                                             float* __restrict__ out) {
    int wid = (int)((blockIdx.x * 256u + threadIdx.x) >> 6);
    int lane = threadIdx.x & 63;
    if (wid >= NN) return;
    float2 acc = *(const float2*)(h + (size_t)wid * KDIM + lane * 2);  // self loop
    unsigned rs = row_start[wid];
    unsigned nk = cnt_in[wid];
    unsigned snext = nk ? csr[rs] : 0u;
    for (unsigned k = 0; k < nk; ++k) {
        unsigned s = snext;
        if (k + 1 < nk) snext = csr[rs + k + 1];
        float2 v = *(const float2*)(h + (size_t)s * KDIM + lane * 2);
        acc.x += v.x;
        acc.y += v.y;
    }
    float si = ii[wid];
    float2 r;
    r.x = acc.x * si;
    r.y = acc.y * si;
    *(float2*)(out + (size_t)wid * KDIM + lane * 2) = r;
}

// ---------------- fp32 GEMM: Y[N,NOUT] = act(A[N,128] @ W[128,NOUT] + b) * oscale ----------------
// 256 threads = (tx 16, ty 16); per-thread 8 rows x CPT cols; A tile transposed in LDS.
template <int NOUT, bool RELU, bool OSCALE>
__global__ __launch_bounds__(256) void k_gemm(const float* __restrict__ A,
                                              const float* __restrict__ W,
                                              const float* __restrict__ bias,
                                              const float* __restrict__ oscale,
                                              float* __restrict__ Y) {
    constexpr int K = 128, BM = 128, KB = 32;
    constexpr int CPT = NOUT / 16;
    __shared__ float As[KB][BM + 1];  // [k][m], +1 pad
    __shared__ float Ws[KB][NOUT];
    const int t = threadIdx.x;
    const int tx = t & 15;
    const int ty = t >> 4;
    const int row0 = blockIdx.x * BM;

    float acc[8][CPT];
#pragma unroll
    for (int j = 0; j < 8; ++j)
#pragma unroll
        for (int c = 0; c < CPT; ++c) acc[j][c] = 0.f;

    for (int k0 = 0; k0 < K; k0 += KB) {
        if (k0) __syncthreads();
        // stage A tile (transpose into LDS)
#pragma unroll
        for (int it = 0; it < 4; ++it) {
            int r = (t >> 3) + 32 * it;
            int kc = (t & 7) * 4;
            int grow = row0 + r;
            float4 v = make_float4(0.f, 0.f, 0.f, 0.f);
            if (grow < NN) v = *(const float4*)(A + (size_t)grow * K + (k0 + kc));
            As[kc + 0][r] = v.x;
            As[kc + 1][r] = v.y;
            As[kc + 2][r] = v.z;
            As[kc + 3][r] = v.w;
        }
        // stage W tile (row-major, already coalesced)
#pragma unroll
        for (int it = 0; it < (KB * NOUT) / 1024; ++it) {
            int idx = t + it * 256;
            int kk = idx / (NOUT / 4);
            int nc = (idx % (NOUT / 4)) * 4;
            *(float4*)(&Ws[kk][nc]) = *(const float4*)(W + (size_t)(k0 + kk) * NOUT + nc);
        }
        __syncthreads();
#pragma unroll
        for (int kk = 0; kk < KB; ++kk) {
            float a[8], w[CPT];
#pragma unroll
            for (int j = 0; j < 8; ++j) a[j] = As[kk][ty * 8 + j];
#pragma unroll
            for (int c = 0; c < CPT; ++c) w[c] = Ws[kk][tx * CPT + c];
#pragma unroll
            for (int j = 0; j < 8; ++j)
#pragma unroll
                for (int c = 0; c < CPT; ++c) acc[j][c] = fmaf(a[j], w[c], acc[j][c]);
        }
    }

#pragma unroll
    for (int j = 0; j < 8; ++j) {
        int grow = row0 + ty * 8 + j;
        if (grow >= NN) continue;
        float os = 1.f;
        if (OSCALE) os = oscale[grow];
#pragma unroll
        for (int c = 0; c < CPT; ++c) {
            float v = acc[j][c] + bias[tx * CPT + c];
            if (RELU) v = fmaxf(v, 0.f);
            Y[(size_t)grow * NOUT + tx * CPT + c] = v * os;
        }
    }
}

extern "C" void kernel_launch(void* const* d_in, const int* in_sizes, int n_in,
                              void* d_out, int out_size, void* d_ws, size_t ws_size,
                              hipStream_t stream) {
    const float* feat = (const float*)d_in[0];
    const int* src = (const int*)d_in[1];
    const int* dst = (const int*)d_in[2];
    const float* W1 = (const float*)d_in[3];
    const float* b1 = (const float*)d_in[4];
    const float* W2 = (const float*)d_in[5];
    const float* b2 = (const float*)d_in[6];
    const float* W3 = (const float*)d_in[7];
    const float* b3 = (const float*)d_in[8];
    float* out = (float*)d_out;

    char* p = (char*)d_ws;
    auto take = [&](size_t bytes) {
        char* q = p;
        p += (bytes + 255) & ~(size_t)255;
        return q;
    };
    unsigned* cnt_out = (unsigned*)take((size_t)NN * 4);
    unsigned* cnt_in = (unsigned*)take((size_t)NN * 4);
    float* oi = (float*)take((size_t)NN * 4);
    float* ii = (float*)take((size_t)NN * 4);
    unsigned* incl = (unsigned*)take((size_t)NN * 4);
    unsigned* bsums = (unsigned*)take(512 * 4);
    unsigned* row_start = (unsigned*)take((size_t)NN * 4);
    unsigned* cursor = (unsigned*)take((size_t)NN * 4);
    unsigned* csr = (unsigned*)take((size_t)NE * 4);
    float* H = (float*)take((size_t)NN * KDIM * 4);
    float* G = (float*)take((size_t)NN * KDIM * 4);

    hipMemsetAsync(cnt_out, 0, (size_t)NN * 4, stream);
    hipMemsetAsync(cnt_in, 0, (size_t)NN * 4, stream);

    const int NB = (NN + 255) / 256;  // 391
    k_degree<<<(NE + 255) / 256, 256, 0, stream>>>(src, dst, cnt_out, cnt_in);
    k_rsqrt<<<NB, 256, 0, stream>>>(cnt_out, cnt_in, oi, ii);
    k_scan1<<<NB, 256, 0, stream>>>(cnt_in, incl, bsums);
    k_scan2<<<1, 512, 0, stream>>>(bsums, NB);
    k_scan3<<<NB, 256, 0, stream>>>(incl, cnt_in, bsums, row_start, cursor);
    k_fill<<<(NE + 255) / 256, 256, 0, stream>>>(src, dst, cursor, csr);

    const int AGG_BLOCKS = NN / 4;  // 4 waves (nodes) per 256-thread block
    const int GEMM_BLOCKS = (NN + 127) / 128;

    // layer 1
    k_agg1<<<AGG_BLOCKS, 256, 0, stream>>>(feat, oi, ii, row_start, cnt_in, csr, G);
    k_gemm<128, true, true><<<GEMM_BLOCKS, 256, 0, stream>>>(G, W1, b1, oi, H);
    // layer 2
    k_agg<<<AGG_BLOCKS, 256, 0, stream>>>(H, ii, row_start, cnt_in, csr, G);
    k_gemm<128, true, true><<<GEMM_BLOCKS, 256, 0, stream>>>(G, W2, b2, oi, H);
    // layer 3
    k_agg<<<AGG_BLOCKS, 256, 0, stream>>>(H, ii, row_start, cnt_in, csr, G);
    k_gemm<64, false, false><<<GEMM_BLOCKS, 256, 0, stream>>>(G, W3, b3, nullptr, out);
}

// Round 2
// 816.353 us; speedup vs baseline: 1.1238x; 1.1238x over previous
//
#include <hip/hip_runtime.h>

#define NN 100000
#define NE 1600000
#define KDIM 128

// ---------------- degree count (self-loop folded in as +1 later) ----------------
__global__ __launch_bounds__(256) void k_degree(const int* __restrict__ src,
                                                const int* __restrict__ dst,
                                                unsigned* __restrict__ cnt_out,
                                                unsigned* __restrict__ cnt_in) {
    int e = blockIdx.x * 256 + threadIdx.x;
    if (e < NE) {
        atomicAdd(&cnt_out[src[e]], 1u);
        atomicAdd(&cnt_in[dst[e]], 1u);
    }
}

__global__ __launch_bounds__(256) void k_rsqrt(const unsigned* __restrict__ cnt_out,
                                               const unsigned* __restrict__ cnt_in,
                                               float* __restrict__ oi,
                                               float* __restrict__ ii) {
    int i = blockIdx.x * 256 + threadIdx.x;
    if (i < NN) {
        oi[i] = rsqrtf((float)(cnt_out[i] + 1u));  // deg includes self loop -> >=1
        ii[i] = rsqrtf((float)(cnt_in[i] + 1u));
    }
}

// ---------------- exclusive scan of in-counts -> CSR row starts ----------------
__global__ __launch_bounds__(256) void k_scan1(const unsigned* __restrict__ cnt,
                                               unsigned* __restrict__ incl,
                                               unsigned* __restrict__ bsums) {
    __shared__ unsigned s[256];
    int i = blockIdx.x * 256 + threadIdx.x;
    unsigned v = (i < NN) ? cnt[i] : 0u;
    s[threadIdx.x] = v;
    __syncthreads();
    for (int off = 1; off < 256; off <<= 1) {
        unsigned x = s[threadIdx.x];
        if (threadIdx.x >= off) x += s[threadIdx.x - off];
        __syncthreads();
        s[threadIdx.x] = x;
        __syncthreads();
    }
    if (i < NN) incl[i] = s[threadIdx.x];
    if (threadIdx.x == 255) bsums[blockIdx.x] = s[255];
}

__global__ __launch_bounds__(512) void k_scan2(unsigned* __restrict__ bsums, int nb) {
    __shared__ unsigned s[512];
    int t = threadIdx.x;
    s[t] = (t < nb) ? bsums[t] : 0u;
    __syncthreads();
    for (int off = 1; off < 512; off <<= 1) {
        unsigned x = s[t];
        if (t >= off) x += s[t - off];
        __syncthreads();
        s[t] = x;
        __syncthreads();
    }
    if (t < nb) bsums[t] = s[t];  // inclusive block sums
}

__global__ __launch_bounds__(256) void k_scan3(const unsigned* __restrict__ incl,
                                               const unsigned* __restrict__ cnt,
                                               const unsigned* __restrict__ bsums,
                                               unsigned* __restrict__ row_start,
                                               unsigned* __restrict__ cursor) {
    int i = blockIdx.x * 256 + threadIdx.x;
    if (i < NN) {
        unsigned prefix = (blockIdx.x > 0) ? bsums[blockIdx.x - 1] : 0u;
        unsigned rs = prefix + incl[i] - cnt[i];  // exclusive
        row_start[i] = rs;
        cursor[i] = rs;
    }
}

__global__ __launch_bounds__(256) void k_fill(const int* __restrict__ src,
                                              const int* __restrict__ dst,
                                              unsigned* __restrict__ cursor,
                                              unsigned* __restrict__ csr) {
    int e = blockIdx.x * 256 + threadIdx.x;
    if (e < NE) {
        unsigned p = atomicAdd(&cursor[dst[e]], 1u);
        csr[p] = (unsigned)src[e];
    }
}

// ---------------- aggregation, 128-wide rows: wave per node ----------------
// 8 independent 512B row-gathers in flight per wave (latency hiding).
// Indices fetched coalesced (csr[rs+lane]) then broadcast via readlane.
template <bool SCALE_SRC>
__global__ __launch_bounds__(256) void k_agg128(const float* __restrict__ h,
                                                const float* __restrict__ oi,
                                                const float* __restrict__ ii,
                                                const unsigned* __restrict__ row_start,
                                                const unsigned* __restrict__ cnt_in,
                                                const unsigned* __restrict__ csr,
                                                float* __restrict__ out) {
    int wid = (int)((blockIdx.x * 256u + threadIdx.x) >> 6);
    int lane = threadIdx.x & 63;
    if (wid >= NN) return;
    const float2* hv = (const float2*)h;
    float2 acc;
    {
        float2 v = hv[(size_t)wid * 64 + lane];
        float sc = SCALE_SRC ? oi[wid] : 1.f;  // self loop
        acc.x = v.x * sc;
        acc.y = v.y * sc;
    }
    unsigned rs = row_start[wid];
    unsigned nk = cnt_in[wid];
    for (unsigned base = 0; base < nk; base += 64) {
        unsigned m = min(64u, nk - base);
        unsigned myidx = ((unsigned)lane < m) ? csr[rs + base + lane] : 0u;
        for (unsigned k = 0; k < m; k += 8) {
            unsigned s[8];
            float sc[8];
            float2 v[8];
#pragma unroll
            for (int i = 0; i < 8; ++i) {
                s[i] = (unsigned)__builtin_amdgcn_readlane((int)myidx, (int)(k + i));
                v[i] = hv[(size_t)s[i] * 64 + lane];
                float w = SCALE_SRC ? oi[s[i]] : 1.f;
                sc[i] = (k + i < m) ? w : 0.f;  // invalid slots load row 0 (hot), weight 0
            }
#pragma unroll
            for (int i = 0; i < 8; ++i) {
                acc.x = fmaf(v[i].x, sc[i], acc.x);
                acc.y = fmaf(v[i].y, sc[i], acc.y);
            }
        }
    }
    float si = ii[wid];
    float2 r;
    r.x = acc.x * si;
    r.y = acc.y * si;
    *(float2*)(out + (size_t)wid * KDIM + lane * 2) = r;
}

// ---------------- aggregation, 64-wide rows (layer 3 reordered: agg after GEMM) ----
// out[n] = ii[n] * (T[n] + sum_neighbors T[s]) + bias   (T already carries oi scale)
__global__ __launch_bounds__(256) void k_agg64(const float* __restrict__ t,
                                               const float* __restrict__ ii,
                                               const float* __restrict__ bias,
                                               const unsigned* __restrict__ row_start,
                                               const unsigned* __restrict__ cnt_in,
                                               const unsigned* __restrict__ csr,
                                               float* __restrict__ out) {
    int wid = (int)((blockIdx.x * 256u + threadIdx.x) >> 6);
    int lane = threadIdx.x & 63;
    if (wid >= NN) return;
    float acc = t[(size_t)wid * 64 + lane];  // self loop
    unsigned rs = row_start[wid];
    unsigned nk = cnt_in[wid];
    for (unsigned base = 0; base < nk; base += 64) {
        unsigned m = min(64u, nk - base);
        unsigned myidx = ((unsigned)lane < m) ? csr[rs + base + lane] : 0u;
        for (unsigned k = 0; k < m; k += 8) {
            unsigned s[8];
            float sc[8];
            float v[8];
#pragma unroll
            for (int i = 0; i < 8; ++i) {
                s[i] = (unsigned)__builtin_amdgcn_readlane((int)myidx, (int)(k + i));
                v[i] = t[(size_t)s[i] * 64 + lane];
                sc[i] = (k + i < m) ? 1.f : 0.f;
            }
#pragma unroll
            for (int i = 0; i < 8; ++i) acc = fmaf(v[i], sc[i], acc);
        }
    }
    out[(size_t)wid * 64 + lane] = acc * ii[wid] + bias[lane];
}

// ---------------- fp32 GEMM: Y[N,NOUT] = act(A[N,128] @ W[128,NOUT] (+b)) * oscale ----
// 256 threads = (tx 16, ty 16); per-thread 8 rows x CPT cols; A tile transposed in LDS.
template <int NOUT, bool RELU, bool OSCALE, bool BIAS>
__global__ __launch_bounds__(256) void k_gemm(const float* __restrict__ A,
                                              const float* __restrict__ W,
                                              const float* __restrict__ bias,
                                              const float* __restrict__ oscale,
                                              float* __restrict__ Y) {
    constexpr int K = 128, BM = 128, KB = 32;
    constexpr int CPT = NOUT / 16;
    __shared__ float As[KB][BM + 1];  // [k][m], +1 pad
    __shared__ float Ws[KB][NOUT];
    const int t = threadIdx.x;
    const int tx = t & 15;
    const int ty = t >> 4;
    const int row0 = blockIdx.x * BM;

    float acc[8][CPT];
#pragma unroll
    for (int j = 0; j < 8; ++j)
#pragma unroll
        for (int c = 0; c < CPT; ++c) acc[j][c] = 0.f;

    for (int k0 = 0; k0 < K; k0 += KB) {
        if (k0) __syncthreads();
        // stage A tile (transpose into LDS)
#pragma unroll
        for (int it = 0; it < 4; ++it) {
            int r = (t >> 3) + 32 * it;
            int kc = (t & 7) * 4;
            int grow = row0 + r;
            float4 v = make_float4(0.f, 0.f, 0.f, 0.f);
            if (grow < NN) v = *(const float4*)(A + (size_t)grow * K + (k0 + kc));
            As[kc + 0][r] = v.x;
            As[kc + 1][r] = v.y;
            As[kc + 2][r] = v.z;
            As[kc + 3][r] = v.w;
        }
        // stage W tile (row-major, already coalesced)
#pragma unroll
        for (int it = 0; it < (KB * NOUT) / 1024; ++it) {
            int idx = t + it * 256;
            int kk = idx / (NOUT / 4);
            int nc = (idx % (NOUT / 4)) * 4;
            *(float4*)(&Ws[kk][nc]) = *(const float4*)(W + (size_t)(k0 + kk) * NOUT + nc);
        }
        __syncthreads();
#pragma unroll
        for (int kk = 0; kk < KB; ++kk) {
            float a[8], w[CPT];
#pragma unroll
            for (int j = 0; j < 8; ++j) a[j] = As[kk][ty * 8 + j];
#pragma unroll
            for (int c = 0; c < CPT; ++c) w[c] = Ws[kk][tx * CPT + c];
#pragma unroll
            for (int j = 0; j < 8; ++j)
#pragma unroll
                for (int c = 0; c < CPT; ++c) acc[j][c] = fmaf(a[j], w[c], acc[j][c]);
        }
    }

#pragma unroll
    for (int j = 0; j < 8; ++j) {
        int grow = row0 + ty * 8 + j;
        if (grow >= NN) continue;
        float os = 1.f;
        if (OSCALE) os = oscale[grow];
#pragma unroll
        for (int c = 0; c < CPT; ++c) {
            float v = acc[j][c];
            if (BIAS) v += bias[tx * CPT + c];
            if (RELU) v = fmaxf(v, 0.f);
            Y[(size_t)grow * NOUT + tx * CPT + c] = v * os;
        }
    }
}

extern "C" void kernel_launch(void* const* d_in, const int* in_sizes, int n_in,
                              void* d_out, int out_size, void* d_ws, size_t ws_size,
                              hipStream_t stream) {
    const float* feat = (const float*)d_in[0];
    const int* src = (const int*)d_in[1];
    const int* dst = (const int*)d_in[2];
    const float* W1 = (const float*)d_in[3];
    const float* b1 = (const float*)d_in[4];
    const float* W2 = (const float*)d_in[5];
    const float* b2 = (const float*)d_in[6];
    const float* W3 = (const float*)d_in[7];
    const float* b3 = (const float*)d_in[8];
    float* out = (float*)d_out;

    char* p = (char*)d_ws;
    auto take = [&](size_t bytes) {
        char* q = p;
        p += (bytes + 255) & ~(size_t)255;
        return q;
    };
    unsigned* cnt_out = (unsigned*)take((size_t)NN * 4);
    unsigned* cnt_in = (unsigned*)take((size_t)NN * 4);
    float* oi = (float*)take((size_t)NN * 4);
    float* ii = (float*)take((size_t)NN * 4);
    unsigned* incl = (unsigned*)take((size_t)NN * 4);
    unsigned* bsums = (unsigned*)take(512 * 4);
    unsigned* row_start = (unsigned*)take((size_t)NN * 4);
    unsigned* cursor = (unsigned*)take((size_t)NN * 4);
    unsigned* csr = (unsigned*)take((size_t)NE * 4);
    float* H = (float*)take((size_t)NN * KDIM * 4);
    float* G = (float*)take((size_t)NN * KDIM * 4);

    hipMemsetAsync(cnt_out, 0, (size_t)NN * 4, stream);
    hipMemsetAsync(cnt_in, 0, (size_t)NN * 4, stream);

    const int NB = (NN + 255) / 256;  // 391
    k_degree<<<(NE + 255) / 256, 256, 0, stream>>>(src, dst, cnt_out, cnt_in);
    k_rsqrt<<<NB, 256, 0, stream>>>(cnt_out, cnt_in, oi, ii);
    k_scan1<<<NB, 256, 0, stream>>>(cnt_in, incl, bsums);
    k_scan2<<<1, 512, 0, stream>>>(bsums, NB);
    k_scan3<<<NB, 256, 0, stream>>>(incl, cnt_in, bsums, row_start, cursor);
    k_fill<<<(NE + 255) / 256, 256, 0, stream>>>(src, dst, cursor, csr);

    const int AGG_BLOCKS = (NN + 3) / 4;  // 4 waves (nodes) per 256-thread block
    const int GEMM_BLOCKS = (NN + 127) / 128;

    // layer 1: agg(feat) -> G, GEMM+bias+relu (+oi prescale for next agg) -> H
    k_agg128<true><<<AGG_BLOCKS, 256, 0, stream>>>(feat, oi, ii, row_start, cnt_in, csr, G);
    k_gemm<128, true, true, true><<<GEMM_BLOCKS, 256, 0, stream>>>(G, W1, b1, oi, H);
    // layer 2
    k_agg128<false><<<AGG_BLOCKS, 256, 0, stream>>>(H, oi, ii, row_start, cnt_in, csr, G);
    k_gemm<128, true, true, true><<<GEMM_BLOCKS, 256, 0, stream>>>(G, W2, b2, oi, H);
    // layer 3 (reordered: agg and GEMM commute; bias added after agg):
    //   T = H @ W3  (H carries oi scale), out = ii * (A_hat T) + b3
    k_gemm<64, false, false, false><<<GEMM_BLOCKS, 256, 0, stream>>>(H, W3, nullptr, nullptr, G);
    k_agg64<<<AGG_BLOCKS, 256, 0, stream>>>(G, ii, b3, row_start, cnt_in, csr, out);
}

// Round 3
// 659.974 us; speedup vs baseline: 1.3901x; 1.2369x over previous
//
#include <hip/hip_runtime.h>

#define NN 100000
#define NE 1600000
#define KDIM 128

// bucket partition parameters: 256 nodes per bucket
#define BSH 8
#define NBKT ((NN + 255) >> BSH)   // 391
#define BCAP 6144                  // >= 28 sigma above mean bucket count (~4092)
#define CHUNK 8192                 // edges per partition block

// ---------------- bucket cursor init ----------------
__global__ __launch_bounds__(512) void k_initcur(unsigned* __restrict__ bucket_cursor) {
    int k = blockIdx.x * 512 + threadIdx.x;
    if (k < NBKT) bucket_cursor[k] = (unsigned)k * BCAP;
}

// ---------------- partition edges into dst-buckets + count out-degrees ----------------
// Writes (src,dst) pairs into per-bucket slabs; within a block, writes to each
// bucket are consecutive (~160B runs) instead of random 4B scatter.
__global__ __launch_bounds__(512) void k_partition(const int* __restrict__ src,
                                                   const int* __restrict__ dst,
                                                   unsigned* __restrict__ cnt_out,
                                                   unsigned* __restrict__ bucket_cursor,
                                                   uint2* __restrict__ part) {
    __shared__ unsigned hist[NBKT];
    __shared__ unsigned base[NBKT];
    const int e0 = blockIdx.x * CHUNK;
    const int lim = min(CHUNK, NE - e0);
    for (int k = threadIdx.x; k < NBKT; k += 512) hist[k] = 0u;
    __syncthreads();
    for (int r = threadIdx.x; r < lim; r += 512)
        atomicAdd(&hist[(unsigned)dst[e0 + r] >> BSH], 1u);
    __syncthreads();
    for (int k = threadIdx.x; k < NBKT; k += 512) {
        unsigned c = hist[k];
        base[k] = c ? atomicAdd(&bucket_cursor[k], c) : 0u;
        hist[k] = 0u;
    }
    __syncthreads();
    for (int r = threadIdx.x; r < lim; r += 512) {
        int s = src[e0 + r];
        int d = dst[e0 + r];
        atomicAdd(&cnt_out[s], 1u);  // out-degree count folded in here
        unsigned k = (unsigned)d >> BSH;
        unsigned p = base[k] + atomicAdd(&hist[k], 1u);
        if (p - (unsigned)k * BCAP < BCAP)  // overflow guard (statistically never)
            part[p] = make_uint2((unsigned)s, (unsigned)d);
    }
}

// ---------------- per-bucket in-degree count (coalesced cnt_in writes) ----------------
__global__ __launch_bounds__(256) void k_cntin(const unsigned* __restrict__ bucket_cursor,
                                               const uint2* __restrict__ part,
                                               unsigned* __restrict__ cnt_in) {
    __shared__ unsigned c[256];
    const int b = blockIdx.x;
    c[threadIdx.x] = 0u;
    __syncthreads();
    unsigned cnt = min(bucket_cursor[b] - (unsigned)b * BCAP, (unsigned)BCAP);
    const uint2* pp = part + (size_t)b * BCAP;
    for (unsigned j = threadIdx.x; j < cnt; j += 256)
        atomicAdd(&c[pp[j].y & 255u], 1u);
    __syncthreads();
    int node = (b << BSH) + threadIdx.x;
    if (node < NN) cnt_in[node] = c[threadIdx.x];
}

__global__ __launch_bounds__(256) void k_rsqrt(const unsigned* __restrict__ cnt_out,
                                               const unsigned* __restrict__ cnt_in,
                                               float* __restrict__ oi,
                                               float* __restrict__ ii) {
    int i = blockIdx.x * 256 + threadIdx.x;
    if (i < NN) {
        oi[i] = rsqrtf((float)(cnt_out[i] + 1u));  // deg includes self loop -> >=1
        ii[i] = rsqrtf((float)(cnt_in[i] + 1u));
    }
}

// ---------------- exclusive scan of in-counts -> CSR row starts ----------------
__global__ __launch_bounds__(256) void k_scan1(const unsigned* __restrict__ cnt,
                                               unsigned* __restrict__ incl,
                                               unsigned* __restrict__ bsums) {
    __shared__ unsigned s[256];
    int i = blockIdx.x * 256 + threadIdx.x;
    unsigned v = (i < NN) ? cnt[i] : 0u;
    s[threadIdx.x] = v;
    __syncthreads();
    for (int off = 1; off < 256; off <<= 1) {
        unsigned x = s[threadIdx.x];
        if (threadIdx.x >= off) x += s[threadIdx.x - off];
        __syncthreads();
        s[threadIdx.x] = x;
        __syncthreads();
    }
    if (i < NN) incl[i] = s[threadIdx.x];
    if (threadIdx.x == 255) bsums[blockIdx.x] = s[255];
}

__global__ __launch_bounds__(512) void k_scan2(unsigned* __restrict__ bsums, int nb) {
    __shared__ unsigned s[512];
    int t = threadIdx.x;
    s[t] = (t < nb) ? bsums[t] : 0u;
    __syncthreads();
    for (int off = 1; off < 512; off <<= 1) {
        unsigned x = s[t];
        if (t >= off) x += s[t - off];
        __syncthreads();
        s[t] = x;
        __syncthreads();
    }
    if (t < nb) bsums[t] = s[t];  // inclusive block sums
}

__global__ __launch_bounds__(256) void k_scan3(const unsigned* __restrict__ incl,
                                               const unsigned* __restrict__ cnt,
                                               const unsigned* __restrict__ bsums,
                                               unsigned* __restrict__ row_start) {
    int i = blockIdx.x * 256 + threadIdx.x;
    if (i < NN) {
        unsigned prefix = (blockIdx.x > 0) ? bsums[blockIdx.x - 1] : 0u;
        row_start[i] = prefix + incl[i] - cnt[i];  // exclusive
    }
}

// ---------------- per-bucket CSR placement: LDS scatter, coalesced global write ----
__global__ __launch_bounds__(256) void k_place(const unsigned* __restrict__ bucket_cursor,
                                               const uint2* __restrict__ part,
                                               const unsigned* __restrict__ row_start,
                                               unsigned* __restrict__ csr) {
    __shared__ unsigned cur[256];
    __shared__ unsigned stage[BCAP];
    const int b = blockIdx.x;
    const int node0 = b << BSH;
    const unsigned seg_base = row_start[node0];
    int node = node0 + threadIdx.x;
    cur[threadIdx.x] = (node < NN) ? row_start[node] - seg_base : 0u;
    __syncthreads();
    unsigned cnt = min(bucket_cursor[b] - (unsigned)b * BCAP, (unsigned)BCAP);
    const uint2* pp = part + (size_t)b * BCAP;
    for (unsigned j = threadIdx.x; j < cnt; j += 256) {
        uint2 e = pp[j];
        unsigned p = atomicAdd(&cur[e.y & 255u], 1u);
        stage[p] = e.x;
    }
    __syncthreads();
    for (unsigned j = threadIdx.x; j < cnt; j += 256)
        csr[seg_base + j] = stage[j];
}

// ---------------- aggregation, 128-wide rows: wave per node ----------------
// 16 independent 512B row-gathers in flight per wave (latency hiding).
template <bool SCALE_SRC>
__global__ __launch_bounds__(256) void k_agg128(const float* __restrict__ h,
                                                const float* __restrict__ oi,
                                                const float* __restrict__ ii,
                                                const unsigned* __restrict__ row_start,
                                                const unsigned* __restrict__ cnt_in,
                                                const unsigned* __restrict__ csr,
                                                float* __restrict__ out) {
    int wid = (int)((blockIdx.x * 256u + threadIdx.x) >> 6);
    int lane = threadIdx.x & 63;
    if (wid >= NN) return;
    const float2* hv = (const float2*)h;
    float2 acc;
    {
        float2 v = hv[(size_t)wid * 64 + lane];
        float sc = SCALE_SRC ? oi[wid] : 1.f;  // self loop
        acc.x = v.x * sc;
        acc.y = v.y * sc;
    }
    unsigned rs = row_start[wid];
    unsigned nk = cnt_in[wid];
    for (unsigned base = 0; base < nk; base += 64) {
        unsigned m = min(64u, nk - base);
        unsigned myidx = ((unsigned)lane < m) ? csr[rs + base + lane] : 0u;
        for (unsigned k = 0; k < m; k += 16) {
            unsigned s[16];
            float sc[16];
            float2 v[16];
#pragma unroll
            for (int i = 0; i < 16; ++i) {
                s[i] = (unsigned)__builtin_amdgcn_readlane((int)myidx, (int)(k + i));
                v[i] = hv[(size_t)s[i] * 64 + lane];
                float w = SCALE_SRC ? oi[s[i]] : 1.f;
                sc[i] = (k + i < m) ? w : 0.f;  // invalid slots load row 0 (hot), weight 0
            }
#pragma unroll
            for (int i = 0; i < 16; ++i) {
                acc.x = fmaf(v[i].x, sc[i], acc.x);
                acc.y = fmaf(v[i].y, sc[i], acc.y);
            }
        }
    }
    float si = ii[wid];
    float2 r;
    r.x = acc.x * si;
    r.y = acc.y * si;
    *(float2*)(out + (size_t)wid * KDIM + lane * 2) = r;
}

// ---------------- aggregation, 64-wide rows (layer 3 reordered: agg after GEMM) ----
// out[n] = ii[n] * (T[n] + sum_neighbors T[s]) + bias   (T already carries oi scale)
__global__ __launch_bounds__(256) void k_agg64(const float* __restrict__ t,
                                               const float* __restrict__ ii,
                                               const float* __restrict__ bias,
                                               const unsigned* __restrict__ row_start,
                                               const unsigned* __restrict__ cnt_in,
                                               const unsigned* __restrict__ csr,
                                               float* __restrict__ out) {
    int wid = (int)((blockIdx.x * 256u + threadIdx.x) >> 6);
    int lane = threadIdx.x & 63;
    if (wid >= NN) return;
    float acc = t[(size_t)wid * 64 + lane];  // self loop
    unsigned rs = row_start[wid];
    unsigned nk = cnt_in[wid];
    for (unsigned base = 0; base < nk; base += 64) {
        unsigned m = min(64u, nk - base);
        unsigned myidx = ((unsigned)lane < m) ? csr[rs + base + lane] : 0u;
        for (unsigned k = 0; k < m; k += 16) {
            unsigned s[16];
            float sc[16];
            float v[16];
#pragma unroll
            for (int i = 0; i < 16; ++i) {
                s[i] = (unsigned)__builtin_amdgcn_readlane((int)myidx, (int)(k + i));
                v[i] = t[(size_t)s[i] * 64 + lane];
                sc[i] = (k + i < m) ? 1.f : 0.f;
            }
#pragma unroll
            for (int i = 0; i < 16; ++i) acc = fmaf(v[i], sc[i], acc);
        }
    }
    out[(size_t)wid * 64 + lane] = acc * ii[wid] + bias[lane];
}

// ---------------- fp32 GEMM: Y[N,NOUT] = act(A[N,128] @ W[128,NOUT] (+b)) * oscale ----
template <int NOUT, bool RELU, bool OSCALE, bool BIAS>
__global__ __launch_bounds__(256) void k_gemm(const float* __restrict__ A,
                                              const float* __restrict__ W,
                                              const float* __restrict__ bias,
                                              const float* __restrict__ oscale,
                                              float* __restrict__ Y) {
    constexpr int K = 128, BM = 128, KB = 32;
    constexpr int CPT = NOUT / 16;
    __shared__ float As[KB][BM + 1];  // [k][m], +1 pad
    __shared__ float Ws[KB][NOUT];
    const int t = threadIdx.x;
    const int tx = t & 15;
    const int ty = t >> 4;
    const int row0 = blockIdx.x * BM;

    float acc[8][CPT];
#pragma unroll
    for (int j = 0; j < 8; ++j)
#pragma unroll
        for (int c = 0; c < CPT; ++c) acc[j][c] = 0.f;

    for (int k0 = 0; k0 < K; k0 += KB) {
        if (k0) __syncthreads();
#pragma unroll
        for (int it = 0; it < 4; ++it) {
            int r = (t >> 3) + 32 * it;
            int kc = (t & 7) * 4;
            int grow = row0 + r;
            float4 v = make_float4(0.f, 0.f, 0.f, 0.f);
            if (grow < NN) v = *(const float4*)(A + (size_t)grow * K + (k0 + kc));
            As[kc + 0][r] = v.x;
            As[kc + 1][r] = v.y;
            As[kc + 2][r] = v.z;
            As[kc + 3][r] = v.w;
        }
#pragma unroll
        for (int it = 0; it < (KB * NOUT) / 1024; ++it) {
            int idx = t + it * 256;
            int kk = idx / (NOUT / 4);
            int nc = (idx % (NOUT / 4)) * 4;
            *(float4*)(&Ws[kk][nc]) = *(const float4*)(W + (size_t)(k0 + kk) * NOUT + nc);
        }
        __syncthreads();
#pragma unroll
        for (int kk = 0; kk < KB; ++kk) {
            float a[8], w[CPT];
#pragma unroll
            for (int j = 0; j < 8; ++j) a[j] = As[kk][ty * 8 + j];
#pragma unroll
            for (int c = 0; c < CPT; ++c) w[c] = Ws[kk][tx * CPT + c];
#pragma unroll
            for (int j = 0; j < 8; ++j)
#pragma unroll
                for (int c = 0; c < CPT; ++c) acc[j][c] = fmaf(a[j], w[c], acc[j][c]);
        }
    }

#pragma unroll
    for (int j = 0; j < 8; ++j) {
        int grow = row0 + ty * 8 + j;
        if (grow >= NN) continue;
        float os = 1.f;
        if (OSCALE) os = oscale[grow];
#pragma unroll
        for (int c = 0; c < CPT; ++c) {
            float v = acc[j][c];
            if (BIAS) v += bias[tx * CPT + c];
            if (RELU) v = fmaxf(v, 0.f);
            Y[(size_t)grow * NOUT + tx * CPT + c] = v * os;
        }
    }
}

extern "C" void kernel_launch(void* const* d_in, const int* in_sizes, int n_in,
                              void* d_out, int out_size, void* d_ws, size_t ws_size,
                              hipStream_t stream) {
    const float* feat = (const float*)d_in[0];
    const int* src = (const int*)d_in[1];
    const int* dst = (const int*)d_in[2];
    const float* W1 = (const float*)d_in[3];
    const float* b1 = (const float*)d_in[4];
    const float* W2 = (const float*)d_in[5];
    const float* b2 = (const float*)d_in[6];
    const float* W3 = (const float*)d_in[7];
    const float* b3 = (const float*)d_in[8];
    float* out = (float*)d_out;

    char* p = (char*)d_ws;
    auto take = [&](size_t bytes) {
        char* q = p;
        p += (bytes + 255) & ~(size_t)255;
        return q;
    };
    unsigned* cnt_out = (unsigned*)take((size_t)NN * 4);
    unsigned* cnt_in = (unsigned*)take((size_t)NN * 4);
    float* oi = (float*)take((size_t)NN * 4);
    float* ii = (float*)take((size_t)NN * 4);
    unsigned* incl = (unsigned*)take((size_t)NN * 4);
    unsigned* bsums = (unsigned*)take(512 * 4);
    unsigned* row_start = (unsigned*)take((size_t)NN * 4);
    unsigned* bucket_cursor = (unsigned*)take((size_t)NBKT * 4);
    unsigned* csr = (unsigned*)take((size_t)NE * 4);
    float* H = (float*)take((size_t)NN * KDIM * 4);
    float* G = (float*)take((size_t)NN * KDIM * 4);
    // part slab aliases H: part is dead before H's first write (layer-1 GEMM)
    uint2* part = (uint2*)H;  // NBKT*BCAP*8 = 19.2 MB <= 51.2 MB

    hipMemsetAsync(cnt_out, 0, (size_t)NN * 4, stream);

    const int NB = (NN + 255) / 256;  // 391
    k_initcur<<<1, 512, 0, stream>>>(bucket_cursor);
    k_partition<<<(NE + CHUNK - 1) / CHUNK, 512, 0, stream>>>(src, dst, cnt_out, bucket_cursor, part);
    k_cntin<<<NBKT, 256, 0, stream>>>(bucket_cursor, part, cnt_in);
    k_rsqrt<<<NB, 256, 0, stream>>>(cnt_out, cnt_in, oi, ii);
    k_scan1<<<NB, 256, 0, stream>>>(cnt_in, incl, bsums);
    k_scan2<<<1, 512, 0, stream>>>(bsums, NB);
    k_scan3<<<NB, 256, 0, stream>>>(incl, cnt_in, bsums, row_start);
    k_place<<<NBKT, 256, 0, stream>>>(bucket_cursor, part, row_start, csr);

    const int AGG_BLOCKS = (NN + 3) / 4;  // 4 waves (nodes) per 256-thread block
    const int GEMM_BLOCKS = (NN + 127) / 128;

    // layer 1: agg(feat) -> G, GEMM+bias+relu (+oi prescale for next agg) -> H
    k_agg128<true><<<AGG_BLOCKS, 256, 0, stream>>>(feat, oi, ii, row_start, cnt_in, csr, G);
    k_gemm<128, true, true, true><<<GEMM_BLOCKS, 256, 0, stream>>>(G, W1, b1, oi, H);
    // layer 2
    k_agg128<false><<<AGG_BLOCKS, 256, 0, stream>>>(H, oi, ii, row_start, cnt_in, csr, G);
    k_gemm<128, true, true, true><<<GEMM_BLOCKS, 256, 0, stream>>>(G, W2, b2, oi, H);
    // layer 3 (reordered: agg and GEMM commute; bias added after agg):
    //   T = H @ W3  (H carries oi scale), out = ii * (A_hat T) + b3
    k_gemm<64, false, false, false><<<GEMM_BLOCKS, 256, 0, stream>>>(H, W3, nullptr, nullptr, G);
    k_agg64<<<AGG_BLOCKS, 256, 0, stream>>>(G, ii, b3, row_start, cnt_in, csr, out);
}

// Round 4
// 540.209 us; speedup vs baseline: 1.6983x; 1.2217x over previous
//
#include <hip/hip_runtime.h>
#include <hip/hip_fp16.h>

#define NN 100000
#define NE 1600000
#define KDIM 128

// bucket partition parameters: 256 nodes per bucket
#define BSH 8
#define NBKT ((NN + 255) >> BSH)   // 391
#define BCAP 6144                  // >= 28 sigma above mean bucket count (~4092)
#define CHUNK 4096                 // edges per partition block

// packed edge: src in bits [0,17), dst&255 in bits [17,25)
#define SRC_MASK 0x1FFFFu

// ---------------- bucket cursor init ----------------
__global__ __launch_bounds__(512) void k_initcur(unsigned* __restrict__ bucket_cursor) {
    int k = blockIdx.x * 512 + threadIdx.x;
    if (k < NBKT) bucket_cursor[k] = (unsigned)k * BCAP;
}

// ---------------- feat -> fp16 copy ----------------
__global__ __launch_bounds__(256) void k_cvt(const float* __restrict__ f,
                                             __half* __restrict__ o) {
    int i = blockIdx.x * 256 + threadIdx.x;
    if (i < NN * KDIM / 4) {
        float4 v = ((const float4*)f)[i];
        __half2 a = __floats2half2_rn(v.x, v.y);
        __half2 b = __floats2half2_rn(v.z, v.w);
        __half2* dst = (__half2*)o + 2 * (size_t)i;
        dst[0] = a;
        dst[1] = b;
    }
}

// ---------------- partition edges into dst-buckets + count out-degrees ----------------
__global__ __launch_bounds__(512) void k_partition(const int* __restrict__ src,
                                                   const int* __restrict__ dst,
                                                   unsigned* __restrict__ cnt_out,
                                                   unsigned* __restrict__ bucket_cursor,
                                                   unsigned* __restrict__ part) {
    __shared__ unsigned hist[NBKT];
    __shared__ unsigned base[NBKT];
    const int e0 = blockIdx.x * CHUNK;
    const int lim = min(CHUNK, NE - e0);
    for (int k = threadIdx.x; k < NBKT; k += 512) hist[k] = 0u;
    __syncthreads();
    for (int r = threadIdx.x; r < lim; r += 512)
        atomicAdd(&hist[(unsigned)dst[e0 + r] >> BSH], 1u);
    __syncthreads();
    for (int k = threadIdx.x; k < NBKT; k += 512) {
        unsigned c = hist[k];
        base[k] = c ? atomicAdd(&bucket_cursor[k], c) : 0u;
        hist[k] = 0u;
    }
    __syncthreads();
    for (int r = threadIdx.x; r < lim; r += 512) {
        unsigned s = (unsigned)src[e0 + r];
        unsigned d = (unsigned)dst[e0 + r];
        atomicAdd(&cnt_out[s], 1u);  // out-degree count folded in here
        unsigned k = d >> BSH;
        unsigned p = base[k] + atomicAdd(&hist[k], 1u);
        if (p - k * BCAP < BCAP)  // overflow guard (statistically never)
            part[p] = s | ((d & 255u) << 17);
    }
}

// ---------------- per-bucket in-degree count (coalesced cnt_in writes) ----------------
__global__ __launch_bounds__(256) void k_cntin(const unsigned* __restrict__ bucket_cursor,
                                               const unsigned* __restrict__ part,
                                               unsigned* __restrict__ cnt_in) {
    __shared__ unsigned c[256];
    const int b = blockIdx.x;
    c[threadIdx.x] = 0u;
    __syncthreads();
    unsigned cnt = min(bucket_cursor[b] - (unsigned)b * BCAP, (unsigned)BCAP);
    const unsigned* pp = part + (size_t)b * BCAP;
    for (unsigned j = threadIdx.x; j < cnt; j += 256)
        atomicAdd(&c[(pp[j] >> 17) & 255u], 1u);
    __syncthreads();
    int node = (b << BSH) + threadIdx.x;
    if (node < NN) cnt_in[node] = c[threadIdx.x];
}

__global__ __launch_bounds__(256) void k_rsqrt(const unsigned* __restrict__ cnt_out,
                                               const unsigned* __restrict__ cnt_in,
                                               float* __restrict__ oi,
                                               float* __restrict__ ii) {
    int i = blockIdx.x * 256 + threadIdx.x;
    if (i < NN) {
        oi[i] = rsqrtf((float)(cnt_out[i] + 1u));  // deg includes self loop -> >=1
        ii[i] = rsqrtf((float)(cnt_in[i] + 1u));
    }
}

// ---------------- exclusive scan of in-counts -> CSR row starts ----------------
__global__ __launch_bounds__(256) void k_scan1(const unsigned* __restrict__ cnt,
                                               unsigned* __restrict__ incl,
                                               unsigned* __restrict__ bsums) {
    __shared__ unsigned s[256];
    int i = blockIdx.x * 256 + threadIdx.x;
    unsigned v = (i < NN) ? cnt[i] : 0u;
    s[threadIdx.x] = v;
    __syncthreads();
    for (int off = 1; off < 256; off <<= 1) {
        unsigned x = s[threadIdx.x];
        if (threadIdx.x >= off) x += s[threadIdx.x - off];
        __syncthreads();
        s[threadIdx.x] = x;
        __syncthreads();
    }
    if (i < NN) incl[i] = s[threadIdx.x];
    if (threadIdx.x == 255) bsums[blockIdx.x] = s[255];
}

__global__ __launch_bounds__(512) void k_scan2(unsigned* __restrict__ bsums, int nb) {
    __shared__ unsigned s[512];
    int t = threadIdx.x;
    s[t] = (t < nb) ? bsums[t] : 0u;
    __syncthreads();
    for (int off = 1; off < 512; off <<= 1) {
        unsigned x = s[t];
        if (t >= off) x += s[t - off];
        __syncthreads();
        s[t] = x;
        __syncthreads();
    }
    if (t < nb) bsums[t] = s[t];  // inclusive block sums
}

__global__ __launch_bounds__(256) void k_scan3(const unsigned* __restrict__ incl,
                                               const unsigned* __restrict__ cnt,
                                               const unsigned* __restrict__ bsums,
                                               unsigned* __restrict__ row_start) {
    int i = blockIdx.x * 256 + threadIdx.x;
    if (i < NN) {
        unsigned prefix = (blockIdx.x > 0) ? bsums[blockIdx.x - 1] : 0u;
        row_start[i] = prefix + incl[i] - cnt[i];  // exclusive
    }
}

// ---------------- per-bucket CSR placement: LDS scatter, coalesced global write ----
__global__ __launch_bounds__(256) void k_place(const unsigned* __restrict__ bucket_cursor,
                                               const unsigned* __restrict__ part,
                                               const unsigned* __restrict__ row_start,
                                               unsigned* __restrict__ csr) {
    __shared__ unsigned cur[256];
    __shared__ unsigned stage[BCAP];
    const int b = blockIdx.x;
    const int node0 = b << BSH;
    const unsigned seg_base = row_start[node0];
    int node = node0 + threadIdx.x;
    cur[threadIdx.x] = (node < NN) ? row_start[node] - seg_base : 0u;
    __syncthreads();
    unsigned cnt = min(bucket_cursor[b] - (unsigned)b * BCAP, (unsigned)BCAP);
    const unsigned* pp = part + (size_t)b * BCAP;
    for (unsigned j = threadIdx.x; j < cnt; j += 256) {
        unsigned e = pp[j];
        unsigned p = atomicAdd(&cur[(e >> 17) & 255u], 1u);
        stage[p] = e & SRC_MASK;
    }
    __syncthreads();
    for (unsigned j = threadIdx.x; j < cnt; j += 256)
        csr[seg_base + j] = stage[j];
}

// ---------------- aggregation, 128-wide fp16 rows: wave per node ----------------
// 16 independent 256B row-gathers in flight per wave.
template <bool SCALE_SRC>
__global__ __launch_bounds__(256) void k_agg128h(const __half* __restrict__ h,
                                                 const float* __restrict__ oi,
                                                 const float* __restrict__ ii,
                                                 const unsigned* __restrict__ row_start,
                                                 const unsigned* __restrict__ cnt_in,
                                                 const unsigned* __restrict__ csr,
                                                 float* __restrict__ out) {
    int wid = (int)((blockIdx.x * 256u + threadIdx.x) >> 6);
    int lane = threadIdx.x & 63;
    if (wid >= NN) return;
    const __half2* hv = (const __half2*)h;
    float2 acc;
    {
        float2 v = __half22float2(hv[(size_t)wid * 64 + lane]);
        float sc = SCALE_SRC ? oi[wid] : 1.f;  // self loop
        acc.x = v.x * sc;
        acc.y = v.y * sc;
    }
    unsigned rs = row_start[wid];
    unsigned nk = cnt_in[wid];
    for (unsigned base = 0; base < nk; base += 64) {
        unsigned m = min(64u, nk - base);
        unsigned myidx = ((unsigned)lane < m) ? csr[rs + base + lane] : 0u;
        for (unsigned k = 0; k < m; k += 16) {
            unsigned s[16];
            float sc[16];
            __half2 v[16];
#pragma unroll
            for (int i = 0; i < 16; ++i) {
                s[i] = (unsigned)__builtin_amdgcn_readlane((int)myidx, (int)(k + i));
                v[i] = hv[(size_t)s[i] * 64 + lane];
                float w = SCALE_SRC ? oi[s[i]] : 1.f;
                sc[i] = (k + i < m) ? w : 0.f;  // invalid slots load row 0 (hot), weight 0
            }
#pragma unroll
            for (int i = 0; i < 16; ++i) {
                float2 f = __half22float2(v[i]);
                acc.x = fmaf(f.x, sc[i], acc.x);
                acc.y = fmaf(f.y, sc[i], acc.y);
            }
        }
    }
    float si = ii[wid];
    float2 r;
    r.x = acc.x * si;
    r.y = acc.y * si;
    *(float2*)(out + (size_t)wid * KDIM + lane * 2) = r;
}

// ---------------- aggregation, 64-wide fp16 rows (layer 3: agg after GEMM) ----
// out[n] = ii[n] * (T[n] + sum_neighbors T[s]) + bias   (T already carries oi scale)
__global__ __launch_bounds__(256) void k_agg64h(const __half* __restrict__ t,
                                                const float* __restrict__ ii,
                                                const float* __restrict__ bias,
                                                const unsigned* __restrict__ row_start,
                                                const unsigned* __restrict__ cnt_in,
                                                const unsigned* __restrict__ csr,
                                                float* __restrict__ out) {
    int wid = (int)((blockIdx.x * 256u + threadIdx.x) >> 6);
    int lane = threadIdx.x & 63;
    if (wid >= NN) return;
    float acc = __half2float(t[(size_t)wid * 64 + lane]);  // self loop
    unsigned rs = row_start[wid];
    unsigned nk = cnt_in[wid];
    for (unsigned base = 0; base < nk; base += 64) {
        unsigned m = min(64u, nk - base);
        unsigned myidx = ((unsigned)lane < m) ? csr[rs + base + lane] : 0u;
        for (unsigned k = 0; k < m; k += 16) {
            unsigned s[16];
            float sc[16];
            __half v[16];
#pragma unroll
            for (int i = 0; i < 16; ++i) {
                s[i] = (unsigned)__builtin_amdgcn_readlane((int)myidx, (int)(k + i));
                v[i] = t[(size_t)s[i] * 64 + lane];
                sc[i] = (k + i < m) ? 1.f : 0.f;
            }
#pragma unroll
            for (int i = 0; i < 16; ++i) acc = fmaf(__half2float(v[i]), sc[i], acc);
        }
    }
    out[(size_t)wid * 64 + lane] = acc * ii[wid] + bias[lane];
}

// ---------------- fp32 GEMM: Y = act(A[N,128] @ W[128,NOUT] (+b)) * oscale ----
// Outputs optionally fp32 (Y32) and/or fp16 (Y16).
template <int NOUT, bool RELU, bool OSCALE, bool BIAS, bool O32, bool O16>
__global__ __launch_bounds__(256) void k_gemm(const float* __restrict__ A,
                                              const float* __restrict__ W,
                                              const float* __restrict__ bias,
                                              const float* __restrict__ oscale,
                                              float* __restrict__ Y32,
                                              __half* __restrict__ Y16) {
    constexpr int K = 128, BM = 128, KB = 32;
    constexpr int CPT = NOUT / 16;
    __shared__ float As[KB][BM + 1];  // [k][m], +1 pad
    __shared__ float Ws[KB][NOUT];
    const int t = threadIdx.x;
    const int tx = t & 15;
    const int ty = t >> 4;
    const int row0 = blockIdx.x * BM;

    float acc[8][CPT];
#pragma unroll
    for (int j = 0; j < 8; ++j)
#pragma unroll
        for (int c = 0; c < CPT; ++c) acc[j][c] = 0.f;

    for (int k0 = 0; k0 < K; k0 += KB) {
        if (k0) __syncthreads();
#pragma unroll
        for (int it = 0; it < 4; ++it) {
            int r = (t >> 3) + 32 * it;
            int kc = (t & 7) * 4;
            int grow = row0 + r;
            float4 v = make_float4(0.f, 0.f, 0.f, 0.f);
            if (grow < NN) v = *(const float4*)(A + (size_t)grow * K + (k0 + kc));
            As[kc + 0][r] = v.x;
            As[kc + 1][r] = v.y;
            As[kc + 2][r] = v.z;
            As[kc + 3][r] = v.w;
        }
#pragma unroll
        for (int it = 0; it < (KB * NOUT) / 1024; ++it) {
            int idx = t + it * 256;
            int kk = idx / (NOUT / 4);
            int nc = (idx % (NOUT / 4)) * 4;
            *(float4*)(&Ws[kk][nc]) = *(const float4*)(W + (size_t)(k0 + kk) * NOUT + nc);
        }
        __syncthreads();
#pragma unroll
        for (int kk = 0; kk < KB; ++kk) {
            float a[8], w[CPT];
#pragma unroll
            for (int j = 0; j < 8; ++j) a[j] = As[kk][ty * 8 + j];
#pragma unroll
            for (int c = 0; c < CPT; ++c) w[c] = Ws[kk][tx * CPT + c];
#pragma unroll
            for (int j = 0; j < 8; ++j)
#pragma unroll
                for (int c = 0; c < CPT; ++c) acc[j][c] = fmaf(a[j], w[c], acc[j][c]);
        }
    }

#pragma unroll
    for (int j = 0; j < 8; ++j) {
        int grow = row0 + ty * 8 + j;
        if (grow >= NN) continue;
        float os = 1.f;
        if (OSCALE) os = oscale[grow];
        float vv[CPT];
#pragma unroll
        for (int c = 0; c < CPT; ++c) {
            float v = acc[j][c];
            if (BIAS) v += bias[tx * CPT + c];
            if (RELU) v = fmaxf(v, 0.f);
            vv[c] = v * os;
        }
        if (O32) {
#pragma unroll
            for (int c = 0; c < CPT; ++c) Y32[(size_t)grow * NOUT + tx * CPT + c] = vv[c];
        }
        if (O16) {
            __half hh[CPT];
#pragma unroll
            for (int c = 0; c < CPT; ++c) hh[c] = __float2half_rn(vv[c]);
            if (CPT == 8)
                *(uint4*)(Y16 + (size_t)grow * NOUT + tx * CPT) = *(uint4*)hh;
            else
                *(uint2*)(Y16 + (size_t)grow * NOUT + tx * CPT) = *(uint2*)hh;
        }
    }
}

extern "C" void kernel_launch(void* const* d_in, const int* in_sizes, int n_in,
                              void* d_out, int out_size, void* d_ws, size_t ws_size,
                              hipStream_t stream) {
    const float* feat = (const float*)d_in[0];
    const int* src = (const int*)d_in[1];
    const int* dst = (const int*)d_in[2];
    const float* W1 = (const float*)d_in[3];
    const float* b1 = (const float*)d_in[4];
    const float* W2 = (const float*)d_in[5];
    const float* b2 = (const float*)d_in[6];
    const float* W3 = (const float*)d_in[7];
    const float* b3 = (const float*)d_in[8];
    float* out = (float*)d_out;

    char* p = (char*)d_ws;
    auto take = [&](size_t bytes) {
        char* q = p;
        p += (bytes + 255) & ~(size_t)255;
        return q;
    };
    unsigned* cnt_out = (unsigned*)take((size_t)NN * 4);
    unsigned* cnt_in = (unsigned*)take((size_t)NN * 4);
    float* oi = (float*)take((size_t)NN * 4);
    float* ii = (float*)take((size_t)NN * 4);
    unsigned* incl = (unsigned*)take((size_t)NN * 4);
    unsigned* bsums = (unsigned*)take(512 * 4);
    unsigned* row_start = (unsigned*)take((size_t)NN * 4);
    unsigned* bucket_cursor = (unsigned*)take((size_t)NBKT * 4);
    unsigned* csr = (unsigned*)take((size_t)NE * 4);
    // region A: 51.2 MB. Holds [feat16 | H16] early, reused as fp32 H2 in layers 2-3.
    char* regionA = take((size_t)NN * KDIM * 4);
    __half* feat16 = (__half*)regionA;                          // 25.6 MB
    __half* H16 = (__half*)(regionA + (size_t)NN * KDIM * 2);   // 25.6 MB
    float* H2 = (float*)regionA;                                // overlays after H16 dead
    float* G = (float*)take((size_t)NN * KDIM * 4);             // fp32 agg output
    // part slab (6.4 MB) / T16 (12.8 MB) share a region: part dead after k_place.
    char* regionB = take((size_t)NN * 64 * 2 > (size_t)NBKT * BCAP * 4
                             ? (size_t)NN * 64 * 2
                             : (size_t)NBKT * BCAP * 4);
    unsigned* part = (unsigned*)regionB;
    __half* T16 = (__half*)regionB;

    hipMemsetAsync(cnt_out, 0, (size_t)NN * 4, stream);

    const int NB = (NN + 255) / 256;  // 391
    k_initcur<<<1, 512, 0, stream>>>(bucket_cursor);
    k_cvt<<<(NN * KDIM / 4 + 255) / 256, 256, 0, stream>>>(feat, feat16);
    k_partition<<<(NE + CHUNK - 1) / CHUNK, 512, 0, stream>>>(src, dst, cnt_out, bucket_cursor, part);
    k_cntin<<<NBKT, 256, 0, stream>>>(bucket_cursor, part, cnt_in);
    k_rsqrt<<<NB, 256, 0, stream>>>(cnt_out, cnt_in, oi, ii);
    k_scan1<<<NB, 256, 0, stream>>>(cnt_in, incl, bsums);
    k_scan2<<<1, 512, 0, stream>>>(bsums, NB);
    k_scan3<<<NB, 256, 0, stream>>>(incl, cnt_in, bsums, row_start);
    k_place<<<NBKT, 256, 0, stream>>>(bucket_cursor, part, row_start, csr);

    const int AGG_BLOCKS = (NN + 3) / 4;  // 4 waves (nodes) per 256-thread block
    const int GEMM_BLOCKS = (NN + 127) / 128;

    // layer 1: agg(feat16) -> G (fp32); GEMM+bias+relu, oi prescale, emit fp16 -> H16
    k_agg128h<true><<<AGG_BLOCKS, 256, 0, stream>>>(feat16, oi, ii, row_start, cnt_in, csr, G);
    k_gemm<128, true, true, true, false, true>
        <<<GEMM_BLOCKS, 256, 0, stream>>>(G, W1, b1, oi, nullptr, H16);
    // layer 2: agg(H16) -> G; GEMM emit fp32 H2 (input to W3 GEMM), oi prescaled
    k_agg128h<false><<<AGG_BLOCKS, 256, 0, stream>>>(H16, oi, ii, row_start, cnt_in, csr, G);
    k_gemm<128, true, true, true, true, false>
        <<<GEMM_BLOCKS, 256, 0, stream>>>(G, W2, b2, oi, H2, nullptr);
    // layer 3 (reordered): T16 = H2 @ W3 (fp16), out = ii * (A_hat T) + b3
    k_gemm<64, false, false, false, false, true>
        <<<GEMM_BLOCKS, 256, 0, stream>>>(H2, W3, nullptr, nullptr, nullptr, T16);
    k_agg64h<<<AGG_BLOCKS, 256, 0, stream>>>(T16, ii, b3, row_start, cnt_in, csr, out);
}

// Round 5
// 345.064 us; speedup vs baseline: 2.6587x; 1.5655x over previous
//
#include <hip/hip_runtime.h>
#include <hip/hip_fp16.h>

#define NN 100000
#define NE 1600000
#define KDIM 128

// bucket partition parameters: 256 nodes per bucket
#define BSH 8
#define NBKT ((NN + 255) >> BSH)   // 391
#define BCAP 6144                  // >= 28 sigma above mean bucket count (~4092)
#define CHUNK 4096                 // edges per partition block

// packed edge: src in bits [0,17), dst&255 in bits [17,25)
#define SRC_MASK 0x1FFFFu

typedef _Float16 half8 __attribute__((ext_vector_type(8)));
typedef float f32x4 __attribute__((ext_vector_type(4)));

// ---------------- bucket cursor init ----------------
__global__ __launch_bounds__(512) void k_initcur(unsigned* __restrict__ bucket_cursor) {
    int k = blockIdx.x * 512 + threadIdx.x;
    if (k < NBKT) bucket_cursor[k] = (unsigned)k * BCAP;
}

// ---------------- feat -> fp16 copy ----------------
__global__ __launch_bounds__(256) void k_cvt(const float* __restrict__ f,
                                             __half* __restrict__ o) {
    int i = blockIdx.x * 256 + threadIdx.x;
    if (i < NN * KDIM / 4) {
        float4 v = ((const float4*)f)[i];
        __half2 a = __floats2half2_rn(v.x, v.y);
        __half2 b = __floats2half2_rn(v.z, v.w);
        __half2* dst = (__half2*)o + 2 * (size_t)i;
        dst[0] = a;
        dst[1] = b;
    }
}

// ---------------- pack W[128,NOUT] fp32 -> MFMA B-fragment order, fp16 ----------------
// Wp element idx = ((kt*NT + nt)*64 + lane)*8 + j  holds  W[kt*32 + (lane>>4)*8 + j][nt*16 + (lane&15)]
template <int NOUT>
__global__ __launch_bounds__(256) void k_packW(const float* __restrict__ W,
                                               _Float16* __restrict__ Wp) {
    constexpr int NT = NOUT / 16;
    int idx = blockIdx.x * 256 + threadIdx.x;
    if (idx >= 128 * NOUT) return;
    int j = idx & 7;
    int l = (idx >> 3) & 63;
    int rest = idx >> 9;
    int nt = rest % NT;
    int kt = rest / NT;
    int k = kt * 32 + ((l >> 4) & 3) * 8 + j;
    int n = nt * 16 + (l & 15);
    Wp[idx] = (_Float16)W[(size_t)k * NOUT + n];
}

// ---------------- partition edges into dst-buckets + count out-degrees ----------------
__global__ __launch_bounds__(512) void k_partition(const int* __restrict__ src,
                                                   const int* __restrict__ dst,
                                                   unsigned* __restrict__ cnt_out,
                                                   unsigned* __restrict__ bucket_cursor,
                                                   unsigned* __restrict__ part) {
    __shared__ unsigned hist[NBKT];
    __shared__ unsigned base[NBKT];
    const int e0 = blockIdx.x * CHUNK;
    const int lim = min(CHUNK, NE - e0);
    for (int k = threadIdx.x; k < NBKT; k += 512) hist[k] = 0u;
    __syncthreads();
    for (int r = threadIdx.x; r < lim; r += 512)
        atomicAdd(&hist[(unsigned)dst[e0 + r] >> BSH], 1u);
    __syncthreads();
    for (int k = threadIdx.x; k < NBKT; k += 512) {
        unsigned c = hist[k];
        base[k] = c ? atomicAdd(&bucket_cursor[k], c) : 0u;
        hist[k] = 0u;
    }
    __syncthreads();
    for (int r = threadIdx.x; r < lim; r += 512) {
        unsigned s = (unsigned)src[e0 + r];
        unsigned d = (unsigned)dst[e0 + r];
        atomicAdd(&cnt_out[s], 1u);  // out-degree count folded in here
        unsigned k = d >> BSH;
        unsigned p = base[k] + atomicAdd(&hist[k], 1u);
        if (p - k * BCAP < BCAP)  // overflow guard (statistically never)
            part[p] = s | ((d & 255u) << 17);
    }
}

// ---------------- per-bucket in-degree count (coalesced cnt_in writes) ----------------
__global__ __launch_bounds__(256) void k_cntin(const unsigned* __restrict__ bucket_cursor,
                                               const unsigned* __restrict__ part,
                                               unsigned* __restrict__ cnt_in) {
    __shared__ unsigned c[256];
    const int b = blockIdx.x;
    c[threadIdx.x] = 0u;
    __syncthreads();
    unsigned cnt = min(bucket_cursor[b] - (unsigned)b * BCAP, (unsigned)BCAP);
    const unsigned* pp = part + (size_t)b * BCAP;
    for (unsigned j = threadIdx.x; j < cnt; j += 256)
        atomicAdd(&c[(pp[j] >> 17) & 255u], 1u);
    __syncthreads();
    int node = (b << BSH) + threadIdx.x;
    if (node < NN) cnt_in[node] = c[threadIdx.x];
}

__global__ __launch_bounds__(256) void k_rsqrt(const unsigned* __restrict__ cnt_out,
                                               const unsigned* __restrict__ cnt_in,
                                               float* __restrict__ oi,
                                               float* __restrict__ ii) {
    int i = blockIdx.x * 256 + threadIdx.x;
    if (i < NN) {
        oi[i] = rsqrtf((float)(cnt_out[i] + 1u));  // deg includes self loop -> >=1
        ii[i] = rsqrtf((float)(cnt_in[i] + 1u));
    }
}

// ---------------- exclusive scan of in-counts -> CSR row starts ----------------
__global__ __launch_bounds__(256) void k_scan1(const unsigned* __restrict__ cnt,
                                               unsigned* __restrict__ incl,
                                               unsigned* __restrict__ bsums) {
    __shared__ unsigned s[256];
    int i = blockIdx.x * 256 + threadIdx.x;
    unsigned v = (i < NN) ? cnt[i] : 0u;
    s[threadIdx.x] = v;
    __syncthreads();
    for (int off = 1; off < 256; off <<= 1) {
        unsigned x = s[threadIdx.x];
        if (threadIdx.x >= off) x += s[threadIdx.x - off];
        __syncthreads();
        s[threadIdx.x] = x;
        __syncthreads();
    }
    if (i < NN) incl[i] = s[threadIdx.x];
    if (threadIdx.x == 255) bsums[blockIdx.x] = s[255];
}

__global__ __launch_bounds__(512) void k_scan2(unsigned* __restrict__ bsums, int nb) {
    __shared__ unsigned s[512];
    int t = threadIdx.x;
    s[t] = (t < nb) ? bsums[t] : 0u;
    __syncthreads();
    for (int off = 1; off < 512; off <<= 1) {
        unsigned x = s[t];
        if (t >= off) x += s[t - off];
        __syncthreads();
        s[t] = x;
        __syncthreads();
    }
    if (t < nb) bsums[t] = s[t];  // inclusive block sums
}

__global__ __launch_bounds__(256) void k_scan3(const unsigned* __restrict__ incl,
                                               const unsigned* __restrict__ cnt,
                                               const unsigned* __restrict__ bsums,
                                               unsigned* __restrict__ row_start) {
    int i = blockIdx.x * 256 + threadIdx.x;
    if (i < NN) {
        unsigned prefix = (blockIdx.x > 0) ? bsums[blockIdx.x - 1] : 0u;
        row_start[i] = prefix + incl[i] - cnt[i];  // exclusive
    }
}

// ---------------- per-bucket CSR placement: LDS scatter, coalesced global write ----
__global__ __launch_bounds__(256) void k_place(const unsigned* __restrict__ bucket_cursor,
                                               const unsigned* __restrict__ part,
                                               const unsigned* __restrict__ row_start,
                                               unsigned* __restrict__ csr) {
    __shared__ unsigned cur[256];
    __shared__ unsigned stage[BCAP];
    const int b = blockIdx.x;
    const int node0 = b << BSH;
    const unsigned seg_base = row_start[node0];
    int node = node0 + threadIdx.x;
    cur[threadIdx.x] = (node < NN) ? row_start[node] - seg_base : 0u;
    __syncthreads();
    unsigned cnt = min(bucket_cursor[b] - (unsigned)b * BCAP, (unsigned)BCAP);
    const unsigned* pp = part + (size_t)b * BCAP;
    for (unsigned j = threadIdx.x; j < cnt; j += 256) {
        unsigned e = pp[j];
        unsigned p = atomicAdd(&cur[(e >> 17) & 255u], 1u);
        stage[p] = e & SRC_MASK;
    }
    __syncthreads();
    for (unsigned j = threadIdx.x; j < cnt; j += 256)
        csr[seg_base + j] = stage[j];
}

// ---------------- aggregation, 128-wide fp16 rows: wave per node, fp16 output ------
// 16 independent 256B row-gathers in flight per wave; fp32 accumulate.
template <bool SCALE_SRC>
__global__ __launch_bounds__(256) void k_agg128h(const __half* __restrict__ h,
                                                 const float* __restrict__ oi,
                                                 const float* __restrict__ ii,
                                                 const unsigned* __restrict__ row_start,
                                                 const unsigned* __restrict__ cnt_in,
                                                 const unsigned* __restrict__ csr,
                                                 __half* __restrict__ out) {
    int wid = (int)((blockIdx.x * 256u + threadIdx.x) >> 6);
    int lane = threadIdx.x & 63;
    if (wid >= NN) return;
    const __half2* hv = (const __half2*)h;
    float2 acc;
    {
        float2 v = __half22float2(hv[(size_t)wid * 64 + lane]);
        float sc = SCALE_SRC ? oi[wid] : 1.f;  // self loop
        acc.x = v.x * sc;
        acc.y = v.y * sc;
    }
    unsigned rs = row_start[wid];
    unsigned nk = cnt_in[wid];
    for (unsigned base = 0; base < nk; base += 64) {
        unsigned m = min(64u, nk - base);
        unsigned myidx = ((unsigned)lane < m) ? csr[rs + base + lane] : 0u;
        for (unsigned k = 0; k < m; k += 16) {
            unsigned s[16];
            float sc[16];
            __half2 v[16];
#pragma unroll
            for (int i = 0; i < 16; ++i) {
                s[i] = (unsigned)__builtin_amdgcn_readlane((int)myidx, (int)(k + i));
                v[i] = hv[(size_t)s[i] * 64 + lane];
                float w = SCALE_SRC ? oi[s[i]] : 1.f;
                sc[i] = (k + i < m) ? w : 0.f;  // invalid slots load row 0 (hot), weight 0
            }
#pragma unroll
            for (int i = 0; i < 16; ++i) {
                float2 f = __half22float2(v[i]);
                acc.x = fmaf(f.x, sc[i], acc.x);
                acc.y = fmaf(f.y, sc[i], acc.y);
            }
        }
    }
    float si = ii[wid];
    ((__half2*)out)[(size_t)wid * 64 + lane] = __floats2half2_rn(acc.x * si, acc.y * si);
}

// ---------------- aggregation, 64-wide fp16 rows (layer 3: agg after GEMM) ----
// out[n] = ii[n] * (T[n] + sum_neighbors T[s]) + bias   (T already carries oi scale)
__global__ __launch_bounds__(256) void k_agg64h(const __half* __restrict__ t,
                                                const float* __restrict__ ii,
                                                const float* __restrict__ bias,
                                                const unsigned* __restrict__ row_start,
                                                const unsigned* __restrict__ cnt_in,
                                                const unsigned* __restrict__ csr,
                                                float* __restrict__ out) {
    int wid = (int)((blockIdx.x * 256u + threadIdx.x) >> 6);
    int lane = threadIdx.x & 63;
    if (wid >= NN) return;
    float acc = __half2float(t[(size_t)wid * 64 + lane]);  // self loop
    unsigned rs = row_start[wid];
    unsigned nk = cnt_in[wid];
    for (unsigned base = 0; base < nk; base += 64) {
        unsigned m = min(64u, nk - base);
        unsigned myidx = ((unsigned)lane < m) ? csr[rs + base + lane] : 0u;
        for (unsigned k = 0; k < m; k += 16) {
            unsigned s[16];
            float sc[16];
            __half v[16];
#pragma unroll
            for (int i = 0; i < 16; ++i) {
                s[i] = (unsigned)__builtin_amdgcn_readlane((int)myidx, (int)(k + i));
                v[i] = t[(size_t)s[i] * 64 + lane];
                sc[i] = (k + i < m) ? 1.f : 0.f;
            }
#pragma unroll
            for (int i = 0; i < 16; ++i) acc = fmaf(__half2float(v[i]), sc[i], acc);
        }
    }
    out[(size_t)wid * 64 + lane] = acc * ii[wid] + bias[lane];
}

// ---------------- fp16 MFMA GEMM: Y = act(A[N,128] @ W[128,NOUT] (+b)) * oscale ----
// 4 waves/block, 16 rows/wave. A frags direct from global (64B-line friendly);
// B frags from pre-packed Wp (contiguous, L2-resident). fp32 accumulate.
template <int NOUT, bool RELU, bool OSCALE, bool BIAS, bool O32, bool O16>
__global__ __launch_bounds__(256) void k_gemmf(const _Float16* __restrict__ A,
                                               const _Float16* __restrict__ Wp,
                                               const float* __restrict__ bias,
                                               const float* __restrict__ oscale,
                                               float* __restrict__ Y32,
                                               _Float16* __restrict__ Y16) {
    constexpr int NT = NOUT / 16;  // n-tiles
    const int w = threadIdx.x >> 6;
    const int l = threadIdx.x & 63;
    const int r0 = blockIdx.x * 64 + w * 16;  // wave's row base
    int arow = r0 + (l & 15);
    if (arow >= NN) arow = NN - 1;  // clamp; outputs guarded below
    const half8* Ap = (const half8*)(A + (size_t)arow * 128) + (l >> 4);  // +4 per k-tile
    const half8* Bp = (const half8*)Wp + l;                               // +(kt*NT+nt)*64

    f32x4 acc[NT];
#pragma unroll
    for (int n = 0; n < NT; ++n) acc[n] = {0.f, 0.f, 0.f, 0.f};

#pragma unroll
    for (int kt = 0; kt < 4; ++kt) {
        half8 a = Ap[kt * 4];
#pragma unroll
        for (int n = 0; n < NT; ++n) {
            half8 b = Bp[(kt * NT + n) * 64];
            acc[n] = __builtin_amdgcn_mfma_f32_16x16x32_f16(a, b, acc[n], 0, 0, 0);
        }
    }

    // C/D layout: col = l&15, row = (l>>4)*4 + j
    const int col = l & 15;
    const int rbase = r0 + (l >> 4) * 4;
#pragma unroll
    for (int j = 0; j < 4; ++j) {
        int row = rbase + j;
        if (row >= NN) continue;
        float os = OSCALE ? oscale[row] : 1.f;
#pragma unroll
        for (int n = 0; n < NT; ++n) {
            float v = acc[n][j];
            if (BIAS) v += bias[n * 16 + col];
            if (RELU) v = fmaxf(v, 0.f);
            v *= os;
            if (O32) Y32[(size_t)row * NOUT + n * 16 + col] = v;
            if (O16) Y16[(size_t)row * NOUT + n * 16 + col] = (_Float16)v;
        }
    }
}

extern "C" void kernel_launch(void* const* d_in, const int* in_sizes, int n_in,
                              void* d_out, int out_size, void* d_ws, size_t ws_size,
                              hipStream_t stream) {
    const float* feat = (const float*)d_in[0];
    const int* src = (const int*)d_in[1];
    const int* dst = (const int*)d_in[2];
    const float* W1 = (const float*)d_in[3];
    const float* b1 = (const float*)d_in[4];
    const float* W2 = (const float*)d_in[5];
    const float* b2 = (const float*)d_in[6];
    const float* W3 = (const float*)d_in[7];
    const float* b3 = (const float*)d_in[8];
    float* out = (float*)d_out;

    char* p = (char*)d_ws;
    auto take = [&](size_t bytes) {
        char* q = p;
        p += (bytes + 255) & ~(size_t)255;
        return q;
    };
    unsigned* cnt_out = (unsigned*)take((size_t)NN * 4);
    unsigned* cnt_in = (unsigned*)take((size_t)NN * 4);
    float* oi = (float*)take((size_t)NN * 4);
    float* ii = (float*)take((size_t)NN * 4);
    unsigned* incl = (unsigned*)take((size_t)NN * 4);
    unsigned* bsums = (unsigned*)take(512 * 4);
    unsigned* row_start = (unsigned*)take((size_t)NN * 4);
    unsigned* bucket_cursor = (unsigned*)take((size_t)NBKT * 4);
    unsigned* csr = (unsigned*)take((size_t)NE * 4);
    __half* feat16 = (__half*)take((size_t)NN * KDIM * 2);
    __half* H16 = (__half*)take((size_t)NN * KDIM * 2);
    __half* G16 = (__half*)take((size_t)NN * KDIM * 2);
    _Float16* Wp1 = (_Float16*)take((size_t)128 * 128 * 2);
    _Float16* Wp2 = (_Float16*)take((size_t)128 * 128 * 2);
    _Float16* Wp3 = (_Float16*)take((size_t)128 * 64 * 2);
    // part slab (9.6 MB) / T16 (12.8 MB) share a region: part dead after k_place.
    char* regionB = take((size_t)NN * 64 * 2 > (size_t)NBKT * BCAP * 4
                             ? (size_t)NN * 64 * 2
                             : (size_t)NBKT * BCAP * 4);
    unsigned* part = (unsigned*)regionB;
    __half* T16 = (__half*)regionB;

    hipMemsetAsync(cnt_out, 0, (size_t)NN * 4, stream);

    const int NB = (NN + 255) / 256;  // 391
    k_initcur<<<1, 512, 0, stream>>>(bucket_cursor);
    k_cvt<<<(NN * KDIM / 4 + 255) / 256, 256, 0, stream>>>(feat, feat16);
    k_packW<128><<<64, 256, 0, stream>>>(W1, Wp1);
    k_packW<128><<<64, 256, 0, stream>>>(W2, Wp2);
    k_packW<64><<<32, 256, 0, stream>>>(W3, Wp3);
    k_partition<<<(NE + CHUNK - 1) / CHUNK, 512, 0, stream>>>(src, dst, cnt_out, bucket_cursor, part);
    k_cntin<<<NBKT, 256, 0, stream>>>(bucket_cursor, part, cnt_in);
    k_rsqrt<<<NB, 256, 0, stream>>>(cnt_out, cnt_in, oi, ii);
    k_scan1<<<NB, 256, 0, stream>>>(cnt_in, incl, bsums);
    k_scan2<<<1, 512, 0, stream>>>(bsums, NB);
    k_scan3<<<NB, 256, 0, stream>>>(incl, cnt_in, bsums, row_start);
    k_place<<<NBKT, 256, 0, stream>>>(bucket_cursor, part, row_start, csr);

    const int AGG_BLOCKS = (NN + 3) / 4;     // 4 waves (nodes) per 256-thread block
    const int GEMM_BLOCKS = (NN + 63) / 64;  // 64 rows per block

    // layer 1: agg(feat16) -> G16; MFMA GEMM +bias+relu, oi prescale -> H16
    k_agg128h<true><<<AGG_BLOCKS, 256, 0, stream>>>(feat16, oi, ii, row_start, cnt_in, csr, G16);
    k_gemmf<128, true, true, true, false, true>
        <<<GEMM_BLOCKS, 256, 0, stream>>>((const _Float16*)G16, Wp1, b1, oi, nullptr, H16 ? (_Float16*)H16 : nullptr);
    // layer 2: agg(H16) -> G16; GEMM -> H16 (in place of layer-1 H, already consumed)
    k_agg128h<false><<<AGG_BLOCKS, 256, 0, stream>>>(H16, oi, ii, row_start, cnt_in, csr, G16);
    k_gemmf<128, true, true, true, false, true>
        <<<GEMM_BLOCKS, 256, 0, stream>>>((const _Float16*)G16, Wp2, b2, oi, nullptr, (_Float16*)H16);
    // layer 3 (reordered): T16 = H16 @ W3; out = ii * (A_hat T) + b3
    k_gemmf<64, false, false, false, false, true>
        <<<GEMM_BLOCKS, 256, 0, stream>>>((const _Float16*)H16, Wp3, nullptr, nullptr, nullptr, (_Float16*)T16);
    k_agg64h<<<AGG_BLOCKS, 256, 0, stream>>>(T16, ii, b3, row_start, cnt_in, csr, out);
}

// Round 6
// 343.115 us; speedup vs baseline: 2.6738x; 1.0057x over previous
//
#include <hip/hip_runtime.h>
#include <hip/hip_fp16.h>

#define NN 100000
#define NE 1600000
#define KDIM 128

// bucket partition parameters: 256 nodes per bucket
#define BSH 8
#define NBKT ((NN + 255) >> BSH)   // 391
#define BCAP 6144                  // >= 28 sigma above mean bucket count (~4092)
#define CHUNK 4096                 // edges per partition block
#define CPAD 16                    // bucket_cursor stride (u32) = 64B line: kills atomic line-contention

// packed edge: src in bits [0,17), dst&255 in bits [17,25)
#define SRC_MASK 0x1FFFFu

typedef _Float16 half8 __attribute__((ext_vector_type(8)));
typedef float f32x4 __attribute__((ext_vector_type(4)));

// ---------------- bucket cursor init ----------------
__global__ __launch_bounds__(512) void k_initcur(unsigned* __restrict__ bucket_cursor) {
    int k = blockIdx.x * 512 + threadIdx.x;
    if (k < NBKT) bucket_cursor[(size_t)k * CPAD] = (unsigned)k * BCAP;
}

// ---------------- feat -> fp16 copy ----------------
__global__ __launch_bounds__(256) void k_cvt(const float* __restrict__ f,
                                             __half* __restrict__ o) {
    int i = blockIdx.x * 256 + threadIdx.x;
    if (i < NN * KDIM / 4) {
        float4 v = ((const float4*)f)[i];
        __half2 a = __floats2half2_rn(v.x, v.y);
        __half2 b = __floats2half2_rn(v.z, v.w);
        __half2* dst = (__half2*)o + 2 * (size_t)i;
        dst[0] = a;
        dst[1] = b;
    }
}

// ---------------- pack W[128,NOUT] fp32 -> MFMA B-fragment order, fp16 ----------------
// Wp element idx = ((kt*NT + nt)*64 + lane)*8 + j  holds  W[kt*32 + (lane>>4)*8 + j][nt*16 + (lane&15)]
template <int NOUT>
__global__ __launch_bounds__(256) void k_packW(const float* __restrict__ W,
                                               _Float16* __restrict__ Wp) {
    constexpr int NT = NOUT / 16;
    int idx = blockIdx.x * 256 + threadIdx.x;
    if (idx >= 128 * NOUT) return;
    int j = idx & 7;
    int l = (idx >> 3) & 63;
    int rest = idx >> 9;
    int nt = rest % NT;
    int kt = rest / NT;
    int k = kt * 32 + ((l >> 4) & 3) * 8 + j;
    int n = nt * 16 + (l & 15);
    Wp[idx] = (_Float16)W[(size_t)k * NOUT + n];
}

// ---------------- partition edges into dst-buckets + count out-degrees ----------------
__global__ __launch_bounds__(512) void k_partition(const int* __restrict__ src,
                                                   const int* __restrict__ dst,
                                                   unsigned* __restrict__ cnt_out,
                                                   unsigned* __restrict__ bucket_cursor,
                                                   unsigned* __restrict__ part) {
    __shared__ unsigned hist[NBKT];
    __shared__ unsigned base[NBKT];
    const int e0 = blockIdx.x * CHUNK;
    const int lim = min(CHUNK, NE - e0);
    for (int k = threadIdx.x; k < NBKT; k += 512) hist[k] = 0u;
    __syncthreads();
    for (int r = threadIdx.x; r < lim; r += 512)
        atomicAdd(&hist[(unsigned)dst[e0 + r] >> BSH], 1u);
    __syncthreads();
    for (int k = threadIdx.x; k < NBKT; k += 512) {
        unsigned c = hist[k];
        base[k] = c ? atomicAdd(&bucket_cursor[(size_t)k * CPAD], c) : 0u;
        hist[k] = 0u;
    }
    __syncthreads();
    for (int r = threadIdx.x; r < lim; r += 512) {
        unsigned s = (unsigned)src[e0 + r];
        unsigned d = (unsigned)dst[e0 + r];
        atomicAdd(&cnt_out[s], 1u);  // out-degree count folded in here
        unsigned k = d >> BSH;
        unsigned p = base[k] + atomicAdd(&hist[k], 1u);
        if (p - k * BCAP < BCAP)  // overflow guard (statistically never)
            part[p] = s | ((d & 255u) << 17);
    }
}

// ---------------- per-bucket in-degree count + both rsqrt norms ----------------
__global__ __launch_bounds__(256) void k_cntin(const unsigned* __restrict__ bucket_cursor,
                                               const unsigned* __restrict__ part,
                                               const unsigned* __restrict__ cnt_out,
                                               unsigned* __restrict__ cnt_in,
                                               float* __restrict__ oi,
                                               float* __restrict__ ii) {
    __shared__ unsigned c[256];
    const int b = blockIdx.x;
    c[threadIdx.x] = 0u;
    __syncthreads();
    unsigned cnt = min(bucket_cursor[(size_t)b * CPAD] - (unsigned)b * BCAP, (unsigned)BCAP);
    const unsigned* pp = part + (size_t)b * BCAP;
    for (unsigned j = threadIdx.x; j < cnt; j += 256)
        atomicAdd(&c[(pp[j] >> 17) & 255u], 1u);
    __syncthreads();
    int node = (b << BSH) + threadIdx.x;
    if (node < NN) {
        unsigned ci = c[threadIdx.x];
        cnt_in[node] = ci;
        ii[node] = rsqrtf((float)(ci + 1u));
        oi[node] = rsqrtf((float)(cnt_out[node] + 1u));  // deg includes self loop
    }
}

// ---------------- exclusive scan of in-counts -> CSR row starts ----------------
__global__ __launch_bounds__(256) void k_scan1(const unsigned* __restrict__ cnt,
                                               unsigned* __restrict__ incl,
                                               unsigned* __restrict__ bsums) {
    __shared__ unsigned s[256];
    int i = blockIdx.x * 256 + threadIdx.x;
    unsigned v = (i < NN) ? cnt[i] : 0u;
    s[threadIdx.x] = v;
    __syncthreads();
    for (int off = 1; off < 256; off <<= 1) {
        unsigned x = s[threadIdx.x];
        if (threadIdx.x >= off) x += s[threadIdx.x - off];
        __syncthreads();
        s[threadIdx.x] = x;
        __syncthreads();
    }
    if (i < NN) incl[i] = s[threadIdx.x];
    if (threadIdx.x == 255) bsums[blockIdx.x] = s[255];
}

__global__ __launch_bounds__(512) void k_scan2(unsigned* __restrict__ bsums, int nb) {
    __shared__ unsigned s[512];
    int t = threadIdx.x;
    s[t] = (t < nb) ? bsums[t] : 0u;
    __syncthreads();
    for (int off = 1; off < 512; off <<= 1) {
        unsigned x = s[t];
        if (t >= off) x += s[t - off];
        __syncthreads();
        s[t] = x;
        __syncthreads();
    }
    if (t < nb) bsums[t] = s[t];  // inclusive block sums
}

__global__ __launch_bounds__(256) void k_scan3(const unsigned* __restrict__ incl,
                                               const unsigned* __restrict__ cnt,
                                               const unsigned* __restrict__ bsums,
                                               unsigned* __restrict__ row_start) {
    int i = blockIdx.x * 256 + threadIdx.x;
    if (i < NN) {
        unsigned prefix = (blockIdx.x > 0) ? bsums[blockIdx.x - 1] : 0u;
        row_start[i] = prefix + incl[i] - cnt[i];  // exclusive
    }
}

// ---------------- per-bucket CSR placement: LDS scatter, coalesced global write ----
__global__ __launch_bounds__(256) void k_place(const unsigned* __restrict__ bucket_cursor,
                                               const unsigned* __restrict__ part,
                                               const unsigned* __restrict__ row_start,
                                               unsigned* __restrict__ csr) {
    __shared__ unsigned cur[256];
    __shared__ unsigned stage[BCAP];
    const int b = blockIdx.x;
    const int node0 = b << BSH;
    const unsigned seg_base = row_start[node0];
    int node = node0 + threadIdx.x;
    cur[threadIdx.x] = (node < NN) ? row_start[node] - seg_base : 0u;
    __syncthreads();
    unsigned cnt = min(bucket_cursor[(size_t)b * CPAD] - (unsigned)b * BCAP, (unsigned)BCAP);
    const unsigned* pp = part + (size_t)b * BCAP;
    for (unsigned j = threadIdx.x; j < cnt; j += 256) {
        unsigned e = pp[j];
        unsigned p = atomicAdd(&cur[(e >> 17) & 255u], 1u);
        stage[p] = e & SRC_MASK;
    }
    __syncthreads();
    for (unsigned j = threadIdx.x; j < cnt; j += 256)
        csr[seg_base + j] = stage[j];
}

// ---------------- aggregation, 128-wide fp16 rows: wave per node, fp16 output ------
// 16 independent 256B row-gathers in flight per wave; fp32 accumulate.
template <bool SCALE_SRC>
__global__ __launch_bounds__(256) void k_agg128h(const __half* __restrict__ h,
                                                 const float* __restrict__ oi,
                                                 const float* __restrict__ ii,
                                                 const unsigned* __restrict__ row_start,
                                                 const unsigned* __restrict__ cnt_in,
                                                 const unsigned* __restrict__ csr,
                                                 __half* __restrict__ out) {
    int wid = (int)((blockIdx.x * 256u + threadIdx.x) >> 6);
    int lane = threadIdx.x & 63;
    if (wid >= NN) return;
    const __half2* hv = (const __half2*)h;
    float2 acc;
    {
        float2 v = __half22float2(hv[(size_t)wid * 64 + lane]);
        float sc = SCALE_SRC ? oi[wid] : 1.f;  // self loop
        acc.x = v.x * sc;
        acc.y = v.y * sc;
    }
    unsigned rs = row_start[wid];
    unsigned nk = cnt_in[wid];
    for (unsigned base = 0; base < nk; base += 64) {
        unsigned m = min(64u, nk - base);
        unsigned myidx = ((unsigned)lane < m) ? csr[rs + base + lane] : 0u;
        for (unsigned k = 0; k < m; k += 16) {
            unsigned s[16];
            float sc[16];
            __half2 v[16];
#pragma unroll
            for (int i = 0; i < 16; ++i) {
                s[i] = (unsigned)__builtin_amdgcn_readlane((int)myidx, (int)(k + i));
                v[i] = hv[(size_t)s[i] * 64 + lane];
                float w = SCALE_SRC ? oi[s[i]] : 1.f;
                sc[i] = (k + i < m) ? w : 0.f;  // invalid slots load row 0 (hot), weight 0
            }
#pragma unroll
            for (int i = 0; i < 16; ++i) {
                float2 f = __half22float2(v[i]);
                acc.x = fmaf(f.x, sc[i], acc.x);
                acc.y = fmaf(f.y, sc[i], acc.y);
            }
        }
    }
    float si = ii[wid];
    ((__half2*)out)[(size_t)wid * 64 + lane] = __floats2half2_rn(acc.x * si, acc.y * si);
}

// ---------------- aggregation, 64-wide fp16 rows (layer 3: agg after GEMM) ----
// out[n] = ii[n] * (T[n] + sum_neighbors T[s]) + bias   (T already carries oi scale)
__global__ __launch_bounds__(256) void k_agg64h(const __half* __restrict__ t,
                                                const float* __restrict__ ii,
                                                const float* __restrict__ bias,
                                                const unsigned* __restrict__ row_start,
                                                const unsigned* __restrict__ cnt_in,
                                                const unsigned* __restrict__ csr,
                                                float* __restrict__ out) {
    int wid = (int)((blockIdx.x * 256u + threadIdx.x) >> 6);
    int lane = threadIdx.x & 63;
    if (wid >= NN) return;
    float acc = __half2float(t[(size_t)wid * 64 + lane]);  // self loop
    unsigned rs = row_start[wid];
    unsigned nk = cnt_in[wid];
    for (unsigned base = 0; base < nk; base += 64) {
        unsigned m = min(64u, nk - base);
        unsigned myidx = ((unsigned)lane < m) ? csr[rs + base + lane] : 0u;
        for (unsigned k = 0; k < m; k += 16) {
            unsigned s[16];
            float sc[16];
            __half v[16];
#pragma unroll
            for (int i = 0; i < 16; ++i) {
                s[i] = (unsigned)__builtin_amdgcn_readlane((int)myidx, (int)(k + i));
                v[i] = t[(size_t)s[i] * 64 + lane];
                sc[i] = (k + i < m) ? 1.f : 0.f;
            }
#pragma unroll
            for (int i = 0; i < 16; ++i) acc = fmaf(__half2float(v[i]), sc[i], acc);
        }
    }
    out[(size_t)wid * 64 + lane] = acc * ii[wid] + bias[lane];
}

// ---------------- fp16 MFMA GEMM: Y = act(A[N,128] @ W[128,NOUT] (+b)) * oscale ----
// 4 waves/block, 16 rows/wave. A frags direct from global (64B-line friendly);
// B frags from pre-packed Wp (contiguous, L2-resident). fp32 accumulate.
template <int NOUT, bool RELU, bool OSCALE, bool BIAS, bool O32, bool O16>
__global__ __launch_bounds__(256) void k_gemmf(const _Float16* __restrict__ A,
                                               const _Float16* __restrict__ Wp,
                                               const float* __restrict__ bias,
                                               const float* __restrict__ oscale,
                                               float* __restrict__ Y32,
                                               _Float16* __restrict__ Y16) {
    constexpr int NT = NOUT / 16;  // n-tiles
    const int w = threadIdx.x >> 6;
    const int l = threadIdx.x & 63;
    const int r0 = blockIdx.x * 64 + w * 16;  // wave's row base
    int arow = r0 + (l & 15);
    if (arow >= NN) arow = NN - 1;  // clamp; outputs guarded below
    const half8* Ap = (const half8*)(A + (size_t)arow * 128) + (l >> 4);  // +4 per k-tile
    const half8* Bp = (const half8*)Wp + l;                               // +(kt*NT+nt)*64

    f32x4 acc[NT];
#pragma unroll
    for (int n = 0; n < NT; ++n) acc[n] = {0.f, 0.f, 0.f, 0.f};

#pragma unroll
    for (int kt = 0; kt < 4; ++kt) {
        half8 a = Ap[kt * 4];
#pragma unroll
        for (int n = 0; n < NT; ++n) {
            half8 b = Bp[(kt * NT + n) * 64];
            acc[n] = __builtin_amdgcn_mfma_f32_16x16x32_f16(a, b, acc[n], 0, 0, 0);
        }
    }

    // C/D layout: col = l&15, row = (l>>4)*4 + j
    const int col = l & 15;
    const int rbase = r0 + (l >> 4) * 4;
#pragma unroll
    for (int j = 0; j < 4; ++j) {
        int row = rbase + j;
        if (row >= NN) continue;
        float os = OSCALE ? oscale[row] : 1.f;
#pragma unroll
        for (int n = 0; n < NT; ++n) {
            float v = acc[n][j];
            if (BIAS) v += bias[n * 16 + col];
            if (RELU) v = fmaxf(v, 0.f);
            v *= os;
            if (O32) Y32[(size_t)row * NOUT + n * 16 + col] = v;
            if (O16) Y16[(size_t)row * NOUT + n * 16 + col] = (_Float16)v;
        }
    }
}

extern "C" void kernel_launch(void* const* d_in, const int* in_sizes, int n_in,
                              void* d_out, int out_size, void* d_ws, size_t ws_size,
                              hipStream_t stream) {
    const float* feat = (const float*)d_in[0];
    const int* src = (const int*)d_in[1];
    const int* dst = (const int*)d_in[2];
    const float* W1 = (const float*)d_in[3];
    const float* b1 = (const float*)d_in[4];
    const float* W2 = (const float*)d_in[5];
    const float* b2 = (const float*)d_in[6];
    const float* W3 = (const float*)d_in[7];
    const float* b3 = (const float*)d_in[8];
    float* out = (float*)d_out;

    char* p = (char*)d_ws;
    auto take = [&](size_t bytes) {
        char* q = p;
        p += (bytes + 255) & ~(size_t)255;
        return q;
    };
    unsigned* cnt_out = (unsigned*)take((size_t)NN * 4);
    unsigned* cnt_in = (unsigned*)take((size_t)NN * 4);
    float* oi = (float*)take((size_t)NN * 4);
    float* ii = (float*)take((size_t)NN * 4);
    unsigned* incl = (unsigned*)take((size_t)NN * 4);
    unsigned* bsums = (unsigned*)take(512 * 4);
    unsigned* row_start = (unsigned*)take((size_t)NN * 4);
    unsigned* bucket_cursor = (unsigned*)take((size_t)NBKT * CPAD * 4);  // 64B-padded
    unsigned* csr = (unsigned*)take((size_t)NE * 4);
    __half* feat16 = (__half*)take((size_t)NN * KDIM * 2);
    __half* H16 = (__half*)take((size_t)NN * KDIM * 2);
    __half* G16 = (__half*)take((size_t)NN * KDIM * 2);
    _Float16* Wp1 = (_Float16*)take((size_t)128 * 128 * 2);
    _Float16* Wp2 = (_Float16*)take((size_t)128 * 128 * 2);
    _Float16* Wp3 = (_Float16*)take((size_t)128 * 64 * 2);
    // part slab (9.6 MB) / T16 (12.8 MB) share a region: part dead after k_place.
    char* regionB = take((size_t)NN * 64 * 2 > (size_t)NBKT * BCAP * 4
                             ? (size_t)NN * 64 * 2
                             : (size_t)NBKT * BCAP * 4);
    unsigned* part = (unsigned*)regionB;
    __half* T16 = (__half*)regionB;

    hipMemsetAsync(cnt_out, 0, (size_t)NN * 4, stream);

    const int NB = (NN + 255) / 256;  // 391
    k_initcur<<<1, 512, 0, stream>>>(bucket_cursor);
    k_cvt<<<(NN * KDIM / 4 + 255) / 256, 256, 0, stream>>>(feat, feat16);
    k_packW<128><<<64, 256, 0, stream>>>(W1, Wp1);
    k_packW<128><<<64, 256, 0, stream>>>(W2, Wp2);
    k_packW<64><<<32, 256, 0, stream>>>(W3, Wp3);
    k_partition<<<(NE + CHUNK - 1) / CHUNK, 512, 0, stream>>>(src, dst, cnt_out, bucket_cursor, part);
    k_cntin<<<NBKT, 256, 0, stream>>>(bucket_cursor, part, cnt_out, cnt_in, oi, ii);
    k_scan1<<<NB, 256, 0, stream>>>(cnt_in, incl, bsums);
    k_scan2<<<1, 512, 0, stream>>>(bsums, NB);
    k_scan3<<<NB, 256, 0, stream>>>(incl, cnt_in, bsums, row_start);
    k_place<<<NBKT, 256, 0, stream>>>(bucket_cursor, part, row_start, csr);

    const int AGG_BLOCKS = (NN + 3) / 4;     // 4 waves (nodes) per 256-thread block
    const int GEMM_BLOCKS = (NN + 63) / 64;  // 64 rows per block

    // layer 1: agg(feat16) -> G16; MFMA GEMM +bias+relu, oi prescale -> H16
    k_agg128h<true><<<AGG_BLOCKS, 256, 0, stream>>>(feat16, oi, ii, row_start, cnt_in, csr, G16);
    k_gemmf<128, true, true, true, false, true>
        <<<GEMM_BLOCKS, 256, 0, stream>>>((const _Float16*)G16, Wp1, b1, oi, nullptr, (_Float16*)H16);
    // layer 2: agg(H16) -> G16; GEMM -> H16 (layer-1 H already consumed)
    k_agg128h<false><<<AGG_BLOCKS, 256, 0, stream>>>(H16, oi, ii, row_start, cnt_in, csr, G16);
    k_gemmf<128, true, true, true, false, true>
        <<<GEMM_BLOCKS, 256, 0, stream>>>((const _Float16*)G16, Wp2, b2, oi, nullptr, (_Float16*)H16);
    // layer 3 (reordered): T16 = H16 @ W3; out = ii * (A_hat T) + b3
    k_gemmf<64, false, false, false, false, true>
        <<<GEMM_BLOCKS, 256, 0, stream>>>((const _Float16*)H16, Wp3, nullptr, nullptr, nullptr, (_Float16*)T16);
    k_agg64h<<<AGG_BLOCKS, 256, 0, stream>>>(T16, ii, b3, row_start, cnt_in, csr, out);
}